// Round 1
// baseline (4364.361 us; speedup 1.0000x reference)
//
#include <hip/hip_runtime.h>

#define N_NODESC 50000
#define N_EDGESC 600000
#define DDIM 128
#define NCLASS 40
#define BN_EPS 1e-5f
#define STAT_BLOCKS 196   // ceil(50000/256)

// ---------------- degree / norm ----------------
__global__ __launch_bounds__(256) void deg_kernel(const int* __restrict__ dst, int* __restrict__ deg) {
    int e = blockIdx.x * 256 + threadIdx.x;
    if (e < N_EDGESC) atomicAdd(&deg[dst[e]], 1);
}

__global__ __launch_bounds__(256) void norm_kernel(const int* __restrict__ deg, float* __restrict__ nrm) {
    int i = blockIdx.x * 256 + threadIdx.x;
    if (i < N_NODESC) {
        float d = (float)deg[i];
        nrm[i] = rsqrtf(fmaxf(d, 1.0f));
    }
}

// ---------------- edge scatter: B[dst] += in[src] * nrm[src] ----------------
// 32 threads per edge, each handles 4 consecutive floats (float4 read, 4 atomics)
__global__ __launch_bounds__(256) void scatter_kernel(const float* __restrict__ in,
                                                      const float* __restrict__ nrm,
                                                      const int* __restrict__ src,
                                                      const int* __restrict__ dst,
                                                      float* __restrict__ outb) {
    long long t = (long long)blockIdx.x * 256 + threadIdx.x;
    int e  = (int)(t >> 5);
    int f4 = (int)(t & 31);
    if (e >= N_EDGESC) return;
    int s = src[e];
    int d = dst[e];
    float ns = nrm[s];
    float4 v = *reinterpret_cast<const float4*>(in + (size_t)s * DDIM + f4 * 4);
    float* o = outb + (size_t)d * DDIM + f4 * 4;
    atomicAdd(o + 0, v.x * ns);
    atomicAdd(o + 1, v.y * ns);
    atomicAdd(o + 2, v.z * ns);
    atomicAdd(o + 3, v.w * ns);
}

// ---------------- BN column stats, stage 1: per-block partial sums ----------------
// block = 256 threads: col = tid&127, row-group = tid>>7; 256 rows per block
__global__ __launch_bounds__(256) void stats_kernel(const float* __restrict__ x,
                                                    const float* __restrict__ nrm,   // nullptr => no row scale
                                                    float* __restrict__ partials) {
    __shared__ float sh[256];
    int col = threadIdx.x & 127;
    int grp = threadIdx.x >> 7;
    int rowEnd = (blockIdx.x + 1) * 256;
    if (rowEnd > N_NODESC) rowEnd = N_NODESC;
    float s = 0.f, q = 0.f;
    for (int r = blockIdx.x * 256 + grp; r < rowEnd; r += 2) {
        float v = x[(size_t)r * DDIM + col];
        if (nrm) v *= nrm[r];
        s += v;
        q += v * v;
    }
    sh[threadIdx.x] = s;
    __syncthreads();
    float s2 = (grp == 0) ? (s + sh[128 + col]) : 0.f;
    __syncthreads();
    sh[threadIdx.x] = q;
    __syncthreads();
    if (grp == 0) {
        float q2 = q + sh[128 + col];
        partials[blockIdx.x * 256 + col]       = s2;
        partials[blockIdx.x * 256 + 128 + col] = q2;
    }
}

// ---------------- BN stats stage 2: mu / rstd (deterministic, fp64 accumulate) ----------------
__global__ void finalize_kernel(const float* __restrict__ partials,
                                float* __restrict__ mu, float* __restrict__ rstd) {
    int col = threadIdx.x;  // 128 threads
    double s = 0.0, q = 0.0;
    for (int b = 0; b < STAT_BLOCKS; b++) {
        s += (double)partials[b * 256 + col];
        q += (double)partials[b * 256 + 128 + col];
    }
    double m = s / (double)N_NODESC;
    double v = q / (double)N_NODESC - m * m;
    if (v < 0.0) v = 0.0;
    mu[col]   = (float)m;
    rstd[col] = rsqrtf((float)v + BN_EPS);
}

// ---------------- fused: A = relu( (B*nrm - mu)*rstd*gamma + beta ) ----------------
__global__ __launch_bounds__(256) void apply_kernel(const float* __restrict__ Bm,
                                                    const float* __restrict__ nrm,
                                                    const float* __restrict__ mu,
                                                    const float* __restrict__ rstd,
                                                    const float* __restrict__ gamma,
                                                    const float* __restrict__ beta,
                                                    float* __restrict__ Am) {
    int t = blockIdx.x * 256 + threadIdx.x;
    int i = t >> 5;
    int f = (t & 31) * 4;
    if (i >= N_NODESC) return;
    float nr = nrm[i];
    float4 v  = *reinterpret_cast<const float4*>(Bm + (size_t)i * DDIM + f);
    float4 m  = *reinterpret_cast<const float4*>(mu + f);
    float4 rs = *reinterpret_cast<const float4*>(rstd + f);
    float4 g  = *reinterpret_cast<const float4*>(gamma + f);
    float4 be = *reinterpret_cast<const float4*>(beta + f);
    float4 o;
    o.x = fmaxf((v.x * nr - m.x) * rs.x * g.x + be.x, 0.f);
    o.y = fmaxf((v.y * nr - m.y) * rs.y * g.y + be.y, 0.f);
    o.z = fmaxf((v.z * nr - m.z) * rs.z * g.z + be.z, 0.f);
    o.w = fmaxf((v.w * nr - m.w) * rs.w * g.w + be.w, 0.f);
    *reinterpret_cast<float4*>(Am + (size_t)i * DDIM + f) = o;
}

// ---------------- GEMM1: X = A @ W1 + b1 (W1 in LDS, 2 rows x 4 cols per thread) ----------------
#define L1_TILE 16
__global__ __launch_bounds__(256) void linear1_kernel(const float* __restrict__ A,
                                                      const float* __restrict__ W1,
                                                      const float* __restrict__ b1,
                                                      float* __restrict__ X) {
    __shared__ float4 Ws[DDIM][DDIM / 4];  // 64 KB, Ws[k][cg] = W1[k][4cg..4cg+3]
    for (int idx = threadIdx.x; idx < DDIM * DDIM / 4; idx += 256) {
        (&Ws[0][0])[idx] = reinterpret_cast<const float4*>(W1)[idx];
    }
    __syncthreads();
    int cg = threadIdx.x & 31;   // column group: cols [4cg, 4cg+4)
    int rp = threadIdx.x >> 5;   // row pair 0..7
    float4 bb = reinterpret_cast<const float4*>(b1)[cg];
    for (int base = blockIdx.x * L1_TILE; base < N_NODESC; base += gridDim.x * L1_TILE) {
        int row0 = base + rp * 2;      // N_NODESC % L1_TILE == 0 -> always valid
        int row1 = row0 + 1;
        const float* r0p = A + (size_t)row0 * DDIM;
        const float* r1p = A + (size_t)row1 * DDIM;
        float4 a0 = make_float4(0.f, 0.f, 0.f, 0.f);
        float4 a1 = make_float4(0.f, 0.f, 0.f, 0.f);
        #pragma unroll 8
        for (int k4 = 0; k4 < DDIM; k4 += 4) {
            float4 x0 = *reinterpret_cast<const float4*>(r0p + k4);
            float4 x1 = *reinterpret_cast<const float4*>(r1p + k4);
            float4 w;
            w = Ws[k4 + 0][cg];
            a0.x += w.x * x0.x; a0.y += w.y * x0.x; a0.z += w.z * x0.x; a0.w += w.w * x0.x;
            a1.x += w.x * x1.x; a1.y += w.y * x1.x; a1.z += w.z * x1.x; a1.w += w.w * x1.x;
            w = Ws[k4 + 1][cg];
            a0.x += w.x * x0.y; a0.y += w.y * x0.y; a0.z += w.z * x0.y; a0.w += w.w * x0.y;
            a1.x += w.x * x1.y; a1.y += w.y * x1.y; a1.z += w.z * x1.y; a1.w += w.w * x1.y;
            w = Ws[k4 + 2][cg];
            a0.x += w.x * x0.z; a0.y += w.y * x0.z; a0.z += w.z * x0.z; a0.w += w.w * x0.z;
            a1.x += w.x * x1.z; a1.y += w.y * x1.z; a1.z += w.z * x1.z; a1.w += w.w * x1.z;
            w = Ws[k4 + 3][cg];
            a0.x += w.x * x0.w; a0.y += w.y * x0.w; a0.z += w.z * x0.w; a0.w += w.w * x0.w;
            a1.x += w.x * x1.w; a1.y += w.y * x1.w; a1.z += w.z * x1.w; a1.w += w.w * x1.w;
        }
        a0.x += bb.x; a0.y += bb.y; a0.z += bb.z; a0.w += bb.w;
        a1.x += bb.x; a1.y += bb.y; a1.z += bb.z; a1.w += bb.w;
        *reinterpret_cast<float4*>(X + (size_t)row0 * DDIM + cg * 4) = a0;
        *reinterpret_cast<float4*>(X + (size_t)row1 * DDIM + cg * 4) = a1;
    }
}

// ---------------- fold BN2 into W2/b2:  W2f = s[k]*W2[k][c],  b2f = b2 + t @ W2 ----------------
__global__ void fold_kernel(const float* __restrict__ W2, const float* __restrict__ b2,
                            const float* __restrict__ g2, const float* __restrict__ be2,
                            const float* __restrict__ mu2, const float* __restrict__ rstd2,
                            float* __restrict__ W2f, float* __restrict__ b2f) {
    __shared__ float s[DDIM], t[DDIM];
    int tid = threadIdx.x;  // 256
    if (tid < DDIM) {
        float sc = rstd2[tid] * g2[tid];
        s[tid] = sc;
        t[tid] = be2[tid] - mu2[tid] * sc;
    }
    __syncthreads();
    for (int idx = tid; idx < DDIM * NCLASS; idx += 256) {
        int k = idx / NCLASS;
        W2f[idx] = W2[idx] * s[k];
    }
    if (tid < NCLASS) {
        float acc = b2[tid];
        for (int k = 0; k < DDIM; k++) acc += t[k] * W2[k * NCLASS + tid];
        b2f[tid] = acc;
    }
}

// ---------------- GEMM2: out = X @ W2f + b2f (W2f in LDS, 2 rows x 5 cols per thread) ----------------
#define L2_TILE 64
__global__ __launch_bounds__(256) void linear2_kernel(const float* __restrict__ X,
                                                      const float* __restrict__ W2f,
                                                      const float* __restrict__ b2f,
                                                      float* __restrict__ out) {
    __shared__ float Ws[DDIM][NCLASS];  // 20 KB
    for (int idx = threadIdx.x; idx < DDIM * NCLASS; idx += 256) {
        (&Ws[0][0])[idx] = W2f[idx];
    }
    __syncthreads();
    int cg = threadIdx.x & 7;    // 5 cols: [5cg, 5cg+5)
    int rp = threadIdx.x >> 3;   // 0..31 -> rows rp*2, rp*2+1
    int c0 = cg * 5;
    for (int base = blockIdx.x * L2_TILE; base < N_NODESC; base += gridDim.x * L2_TILE) {
        int row0 = base + rp * 2;
        int row1 = row0 + 1;
        int r0c = row0 < N_NODESC ? row0 : (N_NODESC - 1);
        int r1c = row1 < N_NODESC ? row1 : (N_NODESC - 1);
        const float* r0p = X + (size_t)r0c * DDIM;
        const float* r1p = X + (size_t)r1c * DDIM;
        float a0[5] = {0.f, 0.f, 0.f, 0.f, 0.f};
        float a1[5] = {0.f, 0.f, 0.f, 0.f, 0.f};
        #pragma unroll 4
        for (int k4 = 0; k4 < DDIM; k4 += 4) {
            float4 x0 = *reinterpret_cast<const float4*>(r0p + k4);
            float4 x1 = *reinterpret_cast<const float4*>(r1p + k4);
            #pragma unroll
            for (int j = 0; j < 5; j++) {
                float w0 = Ws[k4 + 0][c0 + j];
                float w1 = Ws[k4 + 1][c0 + j];
                float w2 = Ws[k4 + 2][c0 + j];
                float w3 = Ws[k4 + 3][c0 + j];
                a0[j] += w0 * x0.x + w1 * x0.y + w2 * x0.z + w3 * x0.w;
                a1[j] += w0 * x1.x + w1 * x1.y + w2 * x1.z + w3 * x1.w;
            }
        }
        if (row0 < N_NODESC) {
            #pragma unroll
            for (int j = 0; j < 5; j++) out[(size_t)row0 * NCLASS + c0 + j] = a0[j] + b2f[c0 + j];
        }
        if (row1 < N_NODESC) {
            #pragma unroll
            for (int j = 0; j < 5; j++) out[(size_t)row1 * NCLASS + c0 + j] = a1[j] + b2f[c0 + j];
        }
    }
}

extern "C" void kernel_launch(void* const* d_in, const int* in_sizes, int n_in,
                              void* d_out, int out_size, void* d_ws, size_t ws_size,
                              hipStream_t stream) {
    const float* h    = (const float*)d_in[0];
    const int*   src  = (const int*)d_in[1];
    const int*   dst  = (const int*)d_in[2];
    const float* bn_g = (const float*)d_in[3];
    const float* bn_b = (const float*)d_in[4];
    const float* W1   = (const float*)d_in[5];
    const float* b1   = (const float*)d_in[6];
    const float* g2   = (const float*)d_in[7];
    const float* be2  = (const float*)d_in[8];
    const float* W2   = (const float*)d_in[9];
    const float* b2   = (const float*)d_in[10];
    float* out = (float*)d_out;

    // workspace layout (floats): ~51.8 MB total
    float* ws   = (float*)d_ws;
    float* nrm  = ws;                                   // N
    int*   deg  = (int*)(ws + N_NODESC);                // N
    float* A    = ws + 2 * N_NODESC;                    // N*D
    float* B    = A + (size_t)N_NODESC * DDIM;          // N*D
    float* partials = B + (size_t)N_NODESC * DDIM;      // STAT_BLOCKS*256
    float* mu   = partials + STAT_BLOCKS * 256;         // 128
    float* rstd = mu + DDIM;                            // 128
    float* W2f  = rstd + DDIM;                          // 128*40
    float* b2f  = W2f + DDIM * NCLASS;                  // 40

    (void)in_sizes; (void)n_in; (void)out_size; (void)ws_size;

    hipMemsetAsync(deg, 0, N_NODESC * sizeof(int), stream);
    deg_kernel<<<(N_EDGESC + 255) / 256, 256, 0, stream>>>(dst, deg);
    norm_kernel<<<(N_NODESC + 255) / 256, 256, 0, stream>>>(deg, nrm);

    for (int l = 0; l < 4; l++) {
        hipMemsetAsync(B, 0, (size_t)N_NODESC * DDIM * sizeof(float), stream);
        scatter_kernel<<<(N_EDGESC * 32) / 256, 256, 0, stream>>>(l == 0 ? h : A, nrm, src, dst, B);
        stats_kernel<<<STAT_BLOCKS, 256, 0, stream>>>(B, nrm, partials);
        finalize_kernel<<<1, 128, 0, stream>>>(partials, mu, rstd);
        apply_kernel<<<(N_NODESC * 32) / 256, 256, 0, stream>>>(B, nrm, mu, rstd, bn_g, bn_b, A);
    }

    linear1_kernel<<<512, 256, 0, stream>>>(A, W1, b1, B);           // X := B
    stats_kernel<<<STAT_BLOCKS, 256, 0, stream>>>(B, nullptr, partials);
    finalize_kernel<<<1, 128, 0, stream>>>(partials, mu, rstd);
    fold_kernel<<<1, 256, 0, stream>>>(W2, b2, g2, be2, mu, rstd, W2f, b2f);
    linear2_kernel<<<512, 256, 0, stream>>>(B, W2f, b2f, out);
}

// Round 2
// 1461.123 us; speedup vs baseline: 2.9870x; 2.9870x over previous
//
#include <hip/hip_runtime.h>

#define N_NODESC 50000
#define N_EDGESC 600000
#define DDIM 128
#define NCLASS 40
#define BN_EPS 1e-5f
#define STAT_BLOCKS 196   // ceil(50000/256)
#define GATHER_BLOCKS 512

// ---------------- degree / norm ----------------
__global__ __launch_bounds__(256) void deg_kernel(const int* __restrict__ dst, int* __restrict__ deg) {
    int e = blockIdx.x * 256 + threadIdx.x;
    if (e < N_EDGESC) atomicAdd(&deg[dst[e]], 1);
}

__global__ __launch_bounds__(256) void norm_kernel(const int* __restrict__ deg, float* __restrict__ nrm) {
    int i = blockIdx.x * 256 + threadIdx.x;
    if (i < N_NODESC) {
        float d = (float)deg[i];
        nrm[i] = rsqrtf(fmaxf(d, 1.0f));
    }
}

// ---------------- exclusive scan of degrees -> rowptr, cursor ----------------
__global__ __launch_bounds__(256) void scan_kernel(const int* __restrict__ deg,
                                                   int* __restrict__ rowptr,
                                                   int* __restrict__ cursor) {
    __shared__ int sh[256];
    __shared__ int carry;
    int t = threadIdx.x;
    if (t == 0) carry = 0;
    __syncthreads();
    for (int base = 0; base < N_NODESC; base += 256) {
        int i = base + t;
        int v = (i < N_NODESC) ? deg[i] : 0;
        sh[t] = v;
        __syncthreads();
        #pragma unroll
        for (int off = 1; off < 256; off <<= 1) {
            int tv = (t >= off) ? sh[t - off] : 0;
            __syncthreads();
            sh[t] += tv;
            __syncthreads();
        }
        int excl = sh[t] - v;
        if (i < N_NODESC) {
            int r = carry + excl;
            rowptr[i] = r;
            cursor[i] = r;
        }
        __syncthreads();
        if (t == 0) carry += sh[255];
        __syncthreads();
    }
    if (t == 0) rowptr[N_NODESC] = N_EDGESC;
}

// ---------------- CSR fill (order nondeterministic, fixed by sort) ----------------
__global__ __launch_bounds__(256) void fill_kernel(const int* __restrict__ src,
                                                   const int* __restrict__ dst,
                                                   int* __restrict__ cursor,
                                                   int* __restrict__ csr) {
    int e = blockIdx.x * 256 + threadIdx.x;
    if (e < N_EDGESC) {
        int d = dst[e];
        int p = atomicAdd(&cursor[d], 1);
        csr[p] = src[e];
    }
}

// ---------------- per-row insertion sort -> deterministic edge order ----------------
__global__ __launch_bounds__(256) void sortrows_kernel(const int* __restrict__ rowptr,
                                                       int* __restrict__ csr) {
    int i = blockIdx.x * 256 + threadIdx.x;
    if (i >= N_NODESC) return;
    int b = rowptr[i], e = rowptr[i + 1];
    for (int j = b + 1; j < e; j++) {
        int v = csr[j];
        int k = j - 1;
        while (k >= b && csr[k] > v) { csr[k + 1] = csr[k]; k--; }
        csr[k + 1] = v;
    }
}

// ---------------- gather: B[i] = nrm[i] * sum_{s in row i} in[s]*nrm[s]; fused BN stats ----------------
// one wave per node; lane&31 = float4 column, lane>>5 = edge parity
__global__ __launch_bounds__(256) void gather_kernel(const float* __restrict__ in,
                                                     const float* __restrict__ nrm,
                                                     const int* __restrict__ rowptr,
                                                     const int* __restrict__ csr,
                                                     float* __restrict__ Bm,
                                                     float* __restrict__ partials) {
    __shared__ float4 red[256];
    int lane = threadIdx.x & 63;
    int wave = threadIdx.x >> 6;   // 0..3
    int half = lane >> 5;          // 0/1
    int c4   = lane & 31;          // float4 index in row
    float4 s = make_float4(0.f, 0.f, 0.f, 0.f);
    float4 q = make_float4(0.f, 0.f, 0.f, 0.f);
    for (int i = blockIdx.x * 4 + wave; i < N_NODESC; i += GATHER_BLOCKS * 4) {
        int b = rowptr[i], e = rowptr[i + 1];
        float4 acc = make_float4(0.f, 0.f, 0.f, 0.f);
        for (int j = b + half; j < e; j += 2) {
            int sidx = csr[j];
            float ns = nrm[sidx];
            float4 v = *reinterpret_cast<const float4*>(in + (size_t)sidx * DDIM + c4 * 4);
            acc.x += v.x * ns; acc.y += v.y * ns; acc.z += v.z * ns; acc.w += v.w * ns;
        }
        acc.x += __shfl_xor(acc.x, 32);
        acc.y += __shfl_xor(acc.y, 32);
        acc.z += __shfl_xor(acc.z, 32);
        acc.w += __shfl_xor(acc.w, 32);
        float ni = nrm[i];
        acc.x *= ni; acc.y *= ni; acc.z *= ni; acc.w *= ni;
        if (half == 0) {
            *reinterpret_cast<float4*>(Bm + (size_t)i * DDIM + c4 * 4) = acc;
            s.x += acc.x; s.y += acc.y; s.z += acc.z; s.w += acc.w;
            q.x += acc.x * acc.x; q.y += acc.y * acc.y; q.z += acc.z * acc.z; q.w += acc.w * acc.w;
        }
    }
    // block-reduce column sums (8 groups of 32 threads map onto same 128 cols)
    red[threadIdx.x] = s;
    __syncthreads();
    if (threadIdx.x < 32) {
        float4 t = red[threadIdx.x];
        #pragma unroll
        for (int k = 1; k < 8; k++) {
            float4 r = red[threadIdx.x + 32 * k];
            t.x += r.x; t.y += r.y; t.z += r.z; t.w += r.w;
        }
        *reinterpret_cast<float4*>(&partials[blockIdx.x * 256 + threadIdx.x * 4]) = t;
    }
    __syncthreads();
    red[threadIdx.x] = q;
    __syncthreads();
    if (threadIdx.x < 32) {
        float4 t = red[threadIdx.x];
        #pragma unroll
        for (int k = 1; k < 8; k++) {
            float4 r = red[threadIdx.x + 32 * k];
            t.x += r.x; t.y += r.y; t.z += r.z; t.w += r.w;
        }
        *reinterpret_cast<float4*>(&partials[blockIdx.x * 256 + 128 + threadIdx.x * 4]) = t;
    }
}

// ---------------- BN column stats for a plain matrix (GEMM1 output) ----------------
__global__ __launch_bounds__(256) void stats_kernel(const float* __restrict__ x,
                                                    float* __restrict__ partials) {
    __shared__ float sh[256];
    int col = threadIdx.x & 127;
    int grp = threadIdx.x >> 7;
    int rowEnd = (blockIdx.x + 1) * 256;
    if (rowEnd > N_NODESC) rowEnd = N_NODESC;
    float s = 0.f, q = 0.f;
    for (int r = blockIdx.x * 256 + grp; r < rowEnd; r += 2) {
        float v = x[(size_t)r * DDIM + col];
        s += v;
        q += v * v;
    }
    sh[threadIdx.x] = s;
    __syncthreads();
    float s2 = (grp == 0) ? (s + sh[128 + col]) : 0.f;
    __syncthreads();
    sh[threadIdx.x] = q;
    __syncthreads();
    if (grp == 0) {
        float q2 = q + sh[128 + col];
        partials[blockIdx.x * 256 + col]       = s2;
        partials[blockIdx.x * 256 + 128 + col] = q2;
    }
}

// ---------------- stats stage 2 ----------------
__global__ void finalize_kernel(const float* __restrict__ partials, int nblocks,
                                float* __restrict__ mu, float* __restrict__ rstd) {
    int col = threadIdx.x;  // 128 threads
    double s = 0.0, q = 0.0;
    for (int b = 0; b < nblocks; b++) {
        s += (double)partials[b * 256 + col];
        q += (double)partials[b * 256 + 128 + col];
    }
    double m = s / (double)N_NODESC;
    double v = q / (double)N_NODESC - m * m;
    if (v < 0.0) v = 0.0;
    mu[col]   = (float)m;
    rstd[col] = rsqrtf((float)v + BN_EPS);
}

// ---------------- fused: A = relu( (B - mu)*rstd*gamma + beta ) ----------------
__global__ __launch_bounds__(256) void apply_kernel(const float* __restrict__ Bm,
                                                    const float* __restrict__ mu,
                                                    const float* __restrict__ rstd,
                                                    const float* __restrict__ gamma,
                                                    const float* __restrict__ beta,
                                                    float* __restrict__ Am) {
    int t = blockIdx.x * 256 + threadIdx.x;
    int i = t >> 5;
    int f = (t & 31) * 4;
    if (i >= N_NODESC) return;
    float4 v  = *reinterpret_cast<const float4*>(Bm + (size_t)i * DDIM + f);
    float4 m  = *reinterpret_cast<const float4*>(mu + f);
    float4 rs = *reinterpret_cast<const float4*>(rstd + f);
    float4 g  = *reinterpret_cast<const float4*>(gamma + f);
    float4 be = *reinterpret_cast<const float4*>(beta + f);
    float4 o;
    o.x = fmaxf((v.x - m.x) * rs.x * g.x + be.x, 0.f);
    o.y = fmaxf((v.y - m.y) * rs.y * g.y + be.y, 0.f);
    o.z = fmaxf((v.z - m.z) * rs.z * g.z + be.z, 0.f);
    o.w = fmaxf((v.w - m.w) * rs.w * g.w + be.w, 0.f);
    *reinterpret_cast<float4*>(Am + (size_t)i * DDIM + f) = o;
}

// ---------------- GEMM1: X = A @ W1 + b1 (W1 in LDS, 2 rows x 4 cols per thread) ----------------
#define L1_TILE 16
__global__ __launch_bounds__(256) void linear1_kernel(const float* __restrict__ A,
                                                      const float* __restrict__ W1,
                                                      const float* __restrict__ b1,
                                                      float* __restrict__ X) {
    __shared__ float4 Ws[DDIM][DDIM / 4];  // 64 KB, Ws[k][cg] = W1[k][4cg..4cg+3]
    for (int idx = threadIdx.x; idx < DDIM * DDIM / 4; idx += 256) {
        (&Ws[0][0])[idx] = reinterpret_cast<const float4*>(W1)[idx];
    }
    __syncthreads();
    int cg = threadIdx.x & 31;   // column group: cols [4cg, 4cg+4)
    int rp = threadIdx.x >> 5;   // row pair 0..7
    float4 bb = reinterpret_cast<const float4*>(b1)[cg];
    for (int base = blockIdx.x * L1_TILE; base < N_NODESC; base += gridDim.x * L1_TILE) {
        int row0 = base + rp * 2;
        int row1 = row0 + 1;
        const float* r0p = A + (size_t)row0 * DDIM;
        const float* r1p = A + (size_t)row1 * DDIM;
        float4 a0 = make_float4(0.f, 0.f, 0.f, 0.f);
        float4 a1 = make_float4(0.f, 0.f, 0.f, 0.f);
        #pragma unroll 8
        for (int k4 = 0; k4 < DDIM; k4 += 4) {
            float4 x0 = *reinterpret_cast<const float4*>(r0p + k4);
            float4 x1 = *reinterpret_cast<const float4*>(r1p + k4);
            float4 w;
            w = Ws[k4 + 0][cg];
            a0.x += w.x * x0.x; a0.y += w.y * x0.x; a0.z += w.z * x0.x; a0.w += w.w * x0.x;
            a1.x += w.x * x1.x; a1.y += w.y * x1.x; a1.z += w.z * x1.x; a1.w += w.w * x1.x;
            w = Ws[k4 + 1][cg];
            a0.x += w.x * x0.y; a0.y += w.y * x0.y; a0.z += w.z * x0.y; a0.w += w.w * x0.y;
            a1.x += w.x * x1.y; a1.y += w.y * x1.y; a1.z += w.z * x1.y; a1.w += w.w * x1.y;
            w = Ws[k4 + 2][cg];
            a0.x += w.x * x0.z; a0.y += w.y * x0.z; a0.z += w.z * x0.z; a0.w += w.w * x0.z;
            a1.x += w.x * x1.z; a1.y += w.y * x1.z; a1.z += w.z * x1.z; a1.w += w.w * x1.z;
            w = Ws[k4 + 3][cg];
            a0.x += w.x * x0.w; a0.y += w.y * x0.w; a0.z += w.z * x0.w; a0.w += w.w * x0.w;
            a1.x += w.x * x1.w; a1.y += w.y * x1.w; a1.z += w.z * x1.w; a1.w += w.w * x1.w;
        }
        a0.x += bb.x; a0.y += bb.y; a0.z += bb.z; a0.w += bb.w;
        a1.x += bb.x; a1.y += bb.y; a1.z += bb.z; a1.w += bb.w;
        *reinterpret_cast<float4*>(X + (size_t)row0 * DDIM + cg * 4) = a0;
        *reinterpret_cast<float4*>(X + (size_t)row1 * DDIM + cg * 4) = a1;
    }
}

// ---------------- fold BN2 into W2/b2 ----------------
__global__ void fold_kernel(const float* __restrict__ W2, const float* __restrict__ b2,
                            const float* __restrict__ g2, const float* __restrict__ be2,
                            const float* __restrict__ mu2, const float* __restrict__ rstd2,
                            float* __restrict__ W2f, float* __restrict__ b2f) {
    __shared__ float s[DDIM], t[DDIM];
    int tid = threadIdx.x;  // 256
    if (tid < DDIM) {
        float sc = rstd2[tid] * g2[tid];
        s[tid] = sc;
        t[tid] = be2[tid] - mu2[tid] * sc;
    }
    __syncthreads();
    for (int idx = tid; idx < DDIM * NCLASS; idx += 256) {
        int k = idx / NCLASS;
        W2f[idx] = W2[idx] * s[k];
    }
    if (tid < NCLASS) {
        float acc = b2[tid];
        for (int k = 0; k < DDIM; k++) acc += t[k] * W2[k * NCLASS + tid];
        b2f[tid] = acc;
    }
}

// ---------------- GEMM2: out = X @ W2f + b2f ----------------
#define L2_TILE 64
__global__ __launch_bounds__(256) void linear2_kernel(const float* __restrict__ X,
                                                      const float* __restrict__ W2f,
                                                      const float* __restrict__ b2f,
                                                      float* __restrict__ out) {
    __shared__ float Ws[DDIM][NCLASS];  // 20 KB
    for (int idx = threadIdx.x; idx < DDIM * NCLASS; idx += 256) {
        (&Ws[0][0])[idx] = W2f[idx];
    }
    __syncthreads();
    int cg = threadIdx.x & 7;    // 5 cols: [5cg, 5cg+5)
    int rp = threadIdx.x >> 3;   // 0..31 -> rows rp*2, rp*2+1
    int c0 = cg * 5;
    for (int base = blockIdx.x * L2_TILE; base < N_NODESC; base += gridDim.x * L2_TILE) {
        int row0 = base + rp * 2;
        int row1 = row0 + 1;
        int r0c = row0 < N_NODESC ? row0 : (N_NODESC - 1);
        int r1c = row1 < N_NODESC ? row1 : (N_NODESC - 1);
        const float* r0p = X + (size_t)r0c * DDIM;
        const float* r1p = X + (size_t)r1c * DDIM;
        float a0[5] = {0.f, 0.f, 0.f, 0.f, 0.f};
        float a1[5] = {0.f, 0.f, 0.f, 0.f, 0.f};
        #pragma unroll 4
        for (int k4 = 0; k4 < DDIM; k4 += 4) {
            float4 x0 = *reinterpret_cast<const float4*>(r0p + k4);
            float4 x1 = *reinterpret_cast<const float4*>(r1p + k4);
            #pragma unroll
            for (int j = 0; j < 5; j++) {
                float w0 = Ws[k4 + 0][c0 + j];
                float w1 = Ws[k4 + 1][c0 + j];
                float w2 = Ws[k4 + 2][c0 + j];
                float w3 = Ws[k4 + 3][c0 + j];
                a0[j] += w0 * x0.x + w1 * x0.y + w2 * x0.z + w3 * x0.w;
                a1[j] += w0 * x1.x + w1 * x1.y + w2 * x1.z + w3 * x1.w;
            }
        }
        if (row0 < N_NODESC) {
            #pragma unroll
            for (int j = 0; j < 5; j++) out[(size_t)row0 * NCLASS + c0 + j] = a0[j] + b2f[c0 + j];
        }
        if (row1 < N_NODESC) {
            #pragma unroll
            for (int j = 0; j < 5; j++) out[(size_t)row1 * NCLASS + c0 + j] = a1[j] + b2f[c0 + j];
        }
    }
}

extern "C" void kernel_launch(void* const* d_in, const int* in_sizes, int n_in,
                              void* d_out, int out_size, void* d_ws, size_t ws_size,
                              hipStream_t stream) {
    const float* h    = (const float*)d_in[0];
    const int*   src  = (const int*)d_in[1];
    const int*   dst  = (const int*)d_in[2];
    const float* bn_g = (const float*)d_in[3];
    const float* bn_b = (const float*)d_in[4];
    const float* W1   = (const float*)d_in[5];
    const float* b1   = (const float*)d_in[6];
    const float* g2   = (const float*)d_in[7];
    const float* be2  = (const float*)d_in[8];
    const float* W2   = (const float*)d_in[9];
    const float* b2   = (const float*)d_in[10];
    float* out = (float*)d_out;

    // workspace layout: ~56 MB
    float* ws     = (float*)d_ws;
    float* nrm    = ws;                                  // N
    int*   deg    = (int*)(ws + N_NODESC);               // N
    int*   cursor = deg + N_NODESC;                      // N
    int*   rowptr = cursor + N_NODESC;                   // N+1 (pad to 50016)
    int*   csr    = rowptr + 50016;                      // E
    float* A      = (float*)(csr + N_EDGESC);            // N*D
    float* B      = A + (size_t)N_NODESC * DDIM;         // N*D
    float* partials = B + (size_t)N_NODESC * DDIM;       // GATHER_BLOCKS*256
    float* mu     = partials + GATHER_BLOCKS * 256;      // 128
    float* rstd   = mu + DDIM;                           // 128
    float* W2f    = rstd + DDIM;                         // 128*40
    float* b2f    = W2f + DDIM * NCLASS;                 // 40

    (void)in_sizes; (void)n_in; (void)out_size; (void)ws_size;

    hipMemsetAsync(deg, 0, N_NODESC * sizeof(int), stream);
    deg_kernel<<<(N_EDGESC + 255) / 256, 256, 0, stream>>>(dst, deg);
    norm_kernel<<<(N_NODESC + 255) / 256, 256, 0, stream>>>(deg, nrm);
    scan_kernel<<<1, 256, 0, stream>>>(deg, rowptr, cursor);
    fill_kernel<<<(N_EDGESC + 255) / 256, 256, 0, stream>>>(src, dst, cursor, csr);
    sortrows_kernel<<<STAT_BLOCKS, 256, 0, stream>>>(rowptr, csr);

    for (int l = 0; l < 4; l++) {
        gather_kernel<<<GATHER_BLOCKS, 256, 0, stream>>>(l == 0 ? h : A, nrm, rowptr, csr, B, partials);
        finalize_kernel<<<1, 128, 0, stream>>>(partials, GATHER_BLOCKS, mu, rstd);
        apply_kernel<<<(N_NODESC * 32) / 256, 256, 0, stream>>>(B, mu, rstd, bn_g, bn_b, A);
    }

    linear1_kernel<<<512, 256, 0, stream>>>(A, W1, b1, B);
    stats_kernel<<<STAT_BLOCKS, 256, 0, stream>>>(B, partials);
    finalize_kernel<<<1, 128, 0, stream>>>(partials, STAT_BLOCKS, mu, rstd);
    fold_kernel<<<1, 256, 0, stream>>>(W2, b2, g2, be2, mu, rstd, W2f, b2f);
    linear2_kernel<<<512, 256, 0, stream>>>(B, W2f, b2f, out);
}

// Round 3
// 647.443 us; speedup vs baseline: 6.7409x; 2.2568x over previous
//
#include <hip/hip_runtime.h>

#define N_NODESC 50000
#define N_EDGESC 600000
#define DDIM 128
#define NCLASS 40
#define BN_EPS 1e-5f
#define STAT_BLOCKS 196     // ceil(50000/256)
#define GATHER_BLOCKS 2048

// ---------------- degree / norm ----------------
__global__ __launch_bounds__(256) void deg_kernel(const int* __restrict__ dst, int* __restrict__ deg) {
    int e = blockIdx.x * 256 + threadIdx.x;
    if (e < N_EDGESC) atomicAdd(&deg[dst[e]], 1);
}

__global__ __launch_bounds__(256) void norm_kernel(const int* __restrict__ deg, float* __restrict__ nrm) {
    int i = blockIdx.x * 256 + threadIdx.x;
    if (i < N_NODESC) {
        float d = (float)deg[i];
        nrm[i] = rsqrtf(fmaxf(d, 1.0f));
    }
}

// ---------------- hierarchical exclusive scan: deg -> rowptr ----------------
__global__ __launch_bounds__(256) void scan1_kernel(const int* __restrict__ deg,
                                                    int* __restrict__ rowptr,
                                                    int* __restrict__ blocksums) {
    __shared__ int sh[256];
    int t = threadIdx.x;
    int i = blockIdx.x * 256 + t;
    int v = (i < N_NODESC) ? deg[i] : 0;
    sh[t] = v;
    __syncthreads();
    #pragma unroll
    for (int off = 1; off < 256; off <<= 1) {
        int tv = (t >= off) ? sh[t - off] : 0;
        __syncthreads();
        sh[t] += tv;
        __syncthreads();
    }
    if (i < N_NODESC) rowptr[i] = sh[t] - v;          // in-block exclusive
    if (t == 255) blocksums[blockIdx.x] = sh[255];
}

__global__ void scan2_kernel(const int* __restrict__ blocksums, int* __restrict__ blockoff) {
    __shared__ int sh[256];
    int t = threadIdx.x;
    int v = (t < STAT_BLOCKS) ? blocksums[t] : 0;
    sh[t] = v;
    __syncthreads();
    #pragma unroll
    for (int off = 1; off < 256; off <<= 1) {
        int tv = (t >= off) ? sh[t - off] : 0;
        __syncthreads();
        sh[t] += tv;
        __syncthreads();
    }
    blockoff[t] = sh[t] - v;                          // exclusive block offsets
}

__global__ __launch_bounds__(256) void scan3_kernel(int* __restrict__ rowptr,
                                                    const int* __restrict__ blockoff,
                                                    int* __restrict__ cursor) {
    int i = blockIdx.x * 256 + threadIdx.x;
    if (i < N_NODESC) {
        int r = rowptr[i] + blockoff[blockIdx.x];
        rowptr[i] = r;
        cursor[i] = r;
    }
    if (blockIdx.x == 0 && threadIdx.x == 0) rowptr[N_NODESC] = N_EDGESC;
}

// ---------------- CSR fill (order nondeterministic, fixed by sort) ----------------
__global__ __launch_bounds__(256) void fill_kernel(const int* __restrict__ src,
                                                   const int* __restrict__ dst,
                                                   int* __restrict__ cursor,
                                                   int* __restrict__ csr) {
    int e = blockIdx.x * 256 + threadIdx.x;
    if (e < N_EDGESC) {
        int d = dst[e];
        int p = atomicAdd(&cursor[d], 1);
        csr[p] = src[e];
    }
}

// ---------------- per-row insertion sort -> deterministic edge order ----------------
__global__ __launch_bounds__(256) void sortrows_kernel(const int* __restrict__ rowptr,
                                                       int* __restrict__ csr) {
    int i = blockIdx.x * 256 + threadIdx.x;
    if (i >= N_NODESC) return;
    int b = rowptr[i], e = rowptr[i + 1];
    for (int j = b + 1; j < e; j++) {
        int v = csr[j];
        int k = j - 1;
        while (k >= b && csr[k] > v) { csr[k + 1] = csr[k]; k--; }
        csr[k + 1] = v;
    }
}

// ---------------- gather with fused BN+ReLU of the PREVIOUS layer ----------------
// out[i] = nrm[i] * sum_{s in row i} nrm[s] * act(in[s])
// act = identity (BN=false, layer 0) or relu(in*sc + sh) (BN=true)
// wave layout: lane>>4 = edge slot (4-way), lane&15 = 8-float column group
template <bool BN>
__global__ __launch_bounds__(256) void gather_kernel(const float* __restrict__ in,
                                                     const float* __restrict__ nrm,
                                                     const int* __restrict__ rowptr,
                                                     const int* __restrict__ csr,
                                                     const float* __restrict__ mu,
                                                     const float* __restrict__ rstd,
                                                     const float* __restrict__ gamma,
                                                     const float* __restrict__ beta,
                                                     float* __restrict__ out) {
    int lane = threadIdx.x & 63;
    int wave = threadIdx.x >> 6;   // 0..3
    int q    = lane >> 4;          // edge slot 0..3
    int col  = (lane & 15) * 8;    // this thread's 8 columns
    float4 sc0, sc1, sh0, sh1;
    if (BN) {
        float4 m0 = *reinterpret_cast<const float4*>(mu + col);
        float4 m1 = *reinterpret_cast<const float4*>(mu + col + 4);
        float4 r0 = *reinterpret_cast<const float4*>(rstd + col);
        float4 r1 = *reinterpret_cast<const float4*>(rstd + col + 4);
        float4 g0 = *reinterpret_cast<const float4*>(gamma + col);
        float4 g1 = *reinterpret_cast<const float4*>(gamma + col + 4);
        float4 b0 = *reinterpret_cast<const float4*>(beta + col);
        float4 b1 = *reinterpret_cast<const float4*>(beta + col + 4);
        sc0.x = r0.x * g0.x; sc0.y = r0.y * g0.y; sc0.z = r0.z * g0.z; sc0.w = r0.w * g0.w;
        sc1.x = r1.x * g1.x; sc1.y = r1.y * g1.y; sc1.z = r1.z * g1.z; sc1.w = r1.w * g1.w;
        sh0.x = b0.x - m0.x * sc0.x; sh0.y = b0.y - m0.y * sc0.y;
        sh0.z = b0.z - m0.z * sc0.z; sh0.w = b0.w - m0.w * sc0.w;
        sh1.x = b1.x - m1.x * sc1.x; sh1.y = b1.y - m1.y * sc1.y;
        sh1.z = b1.z - m1.z * sc1.z; sh1.w = b1.w - m1.w * sc1.w;
    }
    for (int i = blockIdx.x * 4 + wave; i < N_NODESC; i += GATHER_BLOCKS * 4) {
        int b = rowptr[i], e = rowptr[i + 1];
        float4 a0 = make_float4(0.f, 0.f, 0.f, 0.f);
        float4 a1 = make_float4(0.f, 0.f, 0.f, 0.f);
        for (int j = b + q; j < e; j += 4) {
            int sidx = csr[j];
            float ns = nrm[sidx];
            const float* rp = in + (size_t)sidx * DDIM + col;
            float4 v0 = *reinterpret_cast<const float4*>(rp);
            float4 v1 = *reinterpret_cast<const float4*>(rp + 4);
            if (BN) {
                v0.x = fmaxf(v0.x * sc0.x + sh0.x, 0.f);
                v0.y = fmaxf(v0.y * sc0.y + sh0.y, 0.f);
                v0.z = fmaxf(v0.z * sc0.z + sh0.z, 0.f);
                v0.w = fmaxf(v0.w * sc0.w + sh0.w, 0.f);
                v1.x = fmaxf(v1.x * sc1.x + sh1.x, 0.f);
                v1.y = fmaxf(v1.y * sc1.y + sh1.y, 0.f);
                v1.z = fmaxf(v1.z * sc1.z + sh1.z, 0.f);
                v1.w = fmaxf(v1.w * sc1.w + sh1.w, 0.f);
            }
            a0.x += v0.x * ns; a0.y += v0.y * ns; a0.z += v0.z * ns; a0.w += v0.w * ns;
            a1.x += v1.x * ns; a1.y += v1.y * ns; a1.z += v1.z * ns; a1.w += v1.w * ns;
        }
        // reduce across the 4 edge slots (lanes ^16, then ^32)
        a0.x += __shfl_xor(a0.x, 16); a0.y += __shfl_xor(a0.y, 16);
        a0.z += __shfl_xor(a0.z, 16); a0.w += __shfl_xor(a0.w, 16);
        a1.x += __shfl_xor(a1.x, 16); a1.y += __shfl_xor(a1.y, 16);
        a1.z += __shfl_xor(a1.z, 16); a1.w += __shfl_xor(a1.w, 16);
        a0.x += __shfl_xor(a0.x, 32); a0.y += __shfl_xor(a0.y, 32);
        a0.z += __shfl_xor(a0.z, 32); a0.w += __shfl_xor(a0.w, 32);
        a1.x += __shfl_xor(a1.x, 32); a1.y += __shfl_xor(a1.y, 32);
        a1.z += __shfl_xor(a1.z, 32); a1.w += __shfl_xor(a1.w, 32);
        if (q == 0) {
            float ni = nrm[i];
            a0.x *= ni; a0.y *= ni; a0.z *= ni; a0.w *= ni;
            a1.x *= ni; a1.y *= ni; a1.z *= ni; a1.w *= ni;
            float* op = out + (size_t)i * DDIM + col;
            *reinterpret_cast<float4*>(op)     = a0;
            *reinterpret_cast<float4*>(op + 4) = a1;
        }
    }
}

// ---------------- BN column stats (per-block partials) ----------------
__global__ __launch_bounds__(256) void stats_kernel(const float* __restrict__ x,
                                                    float* __restrict__ partials) {
    __shared__ float sh[256];
    int col = threadIdx.x & 127;
    int grp = threadIdx.x >> 7;
    int rowEnd = (blockIdx.x + 1) * 256;
    if (rowEnd > N_NODESC) rowEnd = N_NODESC;
    float s = 0.f, q = 0.f;
    for (int r = blockIdx.x * 256 + grp; r < rowEnd; r += 2) {
        float v = x[(size_t)r * DDIM + col];
        s += v;
        q += v * v;
    }
    sh[threadIdx.x] = s;
    __syncthreads();
    float s2 = (grp == 0) ? (s + sh[128 + col]) : 0.f;
    __syncthreads();
    sh[threadIdx.x] = q;
    __syncthreads();
    if (grp == 0) {
        float q2 = q + sh[128 + col];
        partials[blockIdx.x * 256 + col]       = s2;
        partials[blockIdx.x * 256 + 128 + col] = q2;
    }
}

// ---------------- stats stage 2 ----------------
__global__ void finalize_kernel(const float* __restrict__ partials,
                                float* __restrict__ mu, float* __restrict__ rstd) {
    int col = threadIdx.x;  // 128 threads
    double s = 0.0, q = 0.0;
    for (int b = 0; b < STAT_BLOCKS; b++) {
        s += (double)partials[b * 256 + col];
        q += (double)partials[b * 256 + 128 + col];
    }
    double m = s / (double)N_NODESC;
    double v = q / (double)N_NODESC - m * m;
    if (v < 0.0) v = 0.0;
    mu[col]   = (float)m;
    rstd[col] = rsqrtf((float)v + BN_EPS);
}

// ---------------- GEMM1 with fused input BN+ReLU: X = relu(BN(A)) @ W1 + b1 ----------------
#define L1_TILE 16
__global__ __launch_bounds__(256) void linear1_kernel(const float* __restrict__ A,
                                                      const float* __restrict__ W1,
                                                      const float* __restrict__ b1,
                                                      const float* __restrict__ mu,
                                                      const float* __restrict__ rstd,
                                                      const float* __restrict__ gamma,
                                                      const float* __restrict__ beta,
                                                      float* __restrict__ X) {
    __shared__ float4 Ws[DDIM][DDIM / 4];  // 64 KB
    __shared__ float scs[DDIM], shs[DDIM];
    for (int idx = threadIdx.x; idx < DDIM * DDIM / 4; idx += 256) {
        (&Ws[0][0])[idx] = reinterpret_cast<const float4*>(W1)[idx];
    }
    if (threadIdx.x < DDIM) {
        float a = rstd[threadIdx.x] * gamma[threadIdx.x];
        scs[threadIdx.x] = a;
        shs[threadIdx.x] = beta[threadIdx.x] - mu[threadIdx.x] * a;
    }
    __syncthreads();
    int cg = threadIdx.x & 31;   // cols [4cg, 4cg+4)
    int rp = threadIdx.x >> 5;   // row pair 0..7
    float4 bb = reinterpret_cast<const float4*>(b1)[cg];
    for (int base = blockIdx.x * L1_TILE; base < N_NODESC; base += gridDim.x * L1_TILE) {
        int row0 = base + rp * 2;
        int row1 = row0 + 1;
        const float* r0p = A + (size_t)row0 * DDIM;
        const float* r1p = A + (size_t)row1 * DDIM;
        float4 a0 = make_float4(0.f, 0.f, 0.f, 0.f);
        float4 a1 = make_float4(0.f, 0.f, 0.f, 0.f);
        #pragma unroll 8
        for (int k4 = 0; k4 < DDIM; k4 += 4) {
            float4 x0 = *reinterpret_cast<const float4*>(r0p + k4);
            float4 x1 = *reinterpret_cast<const float4*>(r1p + k4);
            float4 s4 = *reinterpret_cast<const float4*>(&scs[k4]);
            float4 t4 = *reinterpret_cast<const float4*>(&shs[k4]);
            x0.x = fmaxf(x0.x * s4.x + t4.x, 0.f); x0.y = fmaxf(x0.y * s4.y + t4.y, 0.f);
            x0.z = fmaxf(x0.z * s4.z + t4.z, 0.f); x0.w = fmaxf(x0.w * s4.w + t4.w, 0.f);
            x1.x = fmaxf(x1.x * s4.x + t4.x, 0.f); x1.y = fmaxf(x1.y * s4.y + t4.y, 0.f);
            x1.z = fmaxf(x1.z * s4.z + t4.z, 0.f); x1.w = fmaxf(x1.w * s4.w + t4.w, 0.f);
            float4 w;
            w = Ws[k4 + 0][cg];
            a0.x += w.x * x0.x; a0.y += w.y * x0.x; a0.z += w.z * x0.x; a0.w += w.w * x0.x;
            a1.x += w.x * x1.x; a1.y += w.y * x1.x; a1.z += w.z * x1.x; a1.w += w.w * x1.x;
            w = Ws[k4 + 1][cg];
            a0.x += w.x * x0.y; a0.y += w.y * x0.y; a0.z += w.z * x0.y; a0.w += w.w * x0.y;
            a1.x += w.x * x1.y; a1.y += w.y * x1.y; a1.z += w.z * x1.y; a1.w += w.w * x1.y;
            w = Ws[k4 + 2][cg];
            a0.x += w.x * x0.z; a0.y += w.y * x0.z; a0.z += w.z * x0.z; a0.w += w.w * x0.z;
            a1.x += w.x * x1.z; a1.y += w.y * x1.z; a1.z += w.z * x1.z; a1.w += w.w * x1.z;
            w = Ws[k4 + 3][cg];
            a0.x += w.x * x0.w; a0.y += w.y * x0.w; a0.z += w.z * x0.w; a0.w += w.w * x0.w;
            a1.x += w.x * x1.w; a1.y += w.y * x1.w; a1.z += w.z * x1.w; a1.w += w.w * x1.w;
        }
        a0.x += bb.x; a0.y += bb.y; a0.z += bb.z; a0.w += bb.w;
        a1.x += bb.x; a1.y += bb.y; a1.z += bb.z; a1.w += bb.w;
        *reinterpret_cast<float4*>(X + (size_t)row0 * DDIM + cg * 4) = a0;
        *reinterpret_cast<float4*>(X + (size_t)row1 * DDIM + cg * 4) = a1;
    }
}

// ---------------- fold BN2 into W2/b2 ----------------
__global__ void fold_kernel(const float* __restrict__ W2, const float* __restrict__ b2,
                            const float* __restrict__ g2, const float* __restrict__ be2,
                            const float* __restrict__ mu2, const float* __restrict__ rstd2,
                            float* __restrict__ W2f, float* __restrict__ b2f) {
    __shared__ float s[DDIM], t[DDIM];
    int tid = threadIdx.x;  // 256
    if (tid < DDIM) {
        float sc = rstd2[tid] * g2[tid];
        s[tid] = sc;
        t[tid] = be2[tid] - mu2[tid] * sc;
    }
    __syncthreads();
    for (int idx = tid; idx < DDIM * NCLASS; idx += 256) {
        int k = idx / NCLASS;
        W2f[idx] = W2[idx] * s[k];
    }
    if (tid < NCLASS) {
        float acc = b2[tid];
        for (int k = 0; k < DDIM; k++) acc += t[k] * W2[k * NCLASS + tid];
        b2f[tid] = acc;
    }
}

// ---------------- GEMM2: out = X @ W2f + b2f ----------------
#define L2_TILE 64
__global__ __launch_bounds__(256) void linear2_kernel(const float* __restrict__ X,
                                                      const float* __restrict__ W2f,
                                                      const float* __restrict__ b2f,
                                                      float* __restrict__ out) {
    __shared__ float Ws[DDIM][NCLASS];  // 20 KB
    for (int idx = threadIdx.x; idx < DDIM * NCLASS; idx += 256) {
        (&Ws[0][0])[idx] = W2f[idx];
    }
    __syncthreads();
    int cg = threadIdx.x & 7;    // cols [5cg, 5cg+5)
    int rp = threadIdx.x >> 3;   // rows rp*2, rp*2+1
    int c0 = cg * 5;
    for (int base = blockIdx.x * L2_TILE; base < N_NODESC; base += gridDim.x * L2_TILE) {
        int row0 = base + rp * 2;
        int row1 = row0 + 1;
        int r0c = row0 < N_NODESC ? row0 : (N_NODESC - 1);
        int r1c = row1 < N_NODESC ? row1 : (N_NODESC - 1);
        const float* r0p = X + (size_t)r0c * DDIM;
        const float* r1p = X + (size_t)r1c * DDIM;
        float a0[5] = {0.f, 0.f, 0.f, 0.f, 0.f};
        float a1[5] = {0.f, 0.f, 0.f, 0.f, 0.f};
        #pragma unroll 4
        for (int k4 = 0; k4 < DDIM; k4 += 4) {
            float4 x0 = *reinterpret_cast<const float4*>(r0p + k4);
            float4 x1 = *reinterpret_cast<const float4*>(r1p + k4);
            #pragma unroll
            for (int j = 0; j < 5; j++) {
                float w0 = Ws[k4 + 0][c0 + j];
                float w1 = Ws[k4 + 1][c0 + j];
                float w2 = Ws[k4 + 2][c0 + j];
                float w3 = Ws[k4 + 3][c0 + j];
                a0[j] += w0 * x0.x + w1 * x0.y + w2 * x0.z + w3 * x0.w;
                a1[j] += w0 * x1.x + w1 * x1.y + w2 * x1.z + w3 * x1.w;
            }
        }
        if (row0 < N_NODESC) {
            #pragma unroll
            for (int j = 0; j < 5; j++) out[(size_t)row0 * NCLASS + c0 + j] = a0[j] + b2f[c0 + j];
        }
        if (row1 < N_NODESC) {
            #pragma unroll
            for (int j = 0; j < 5; j++) out[(size_t)row1 * NCLASS + c0 + j] = a1[j] + b2f[c0 + j];
        }
    }
}

extern "C" void kernel_launch(void* const* d_in, const int* in_sizes, int n_in,
                              void* d_out, int out_size, void* d_ws, size_t ws_size,
                              hipStream_t stream) {
    const float* h    = (const float*)d_in[0];
    const int*   src  = (const int*)d_in[1];
    const int*   dst  = (const int*)d_in[2];
    const float* bn_g = (const float*)d_in[3];
    const float* bn_b = (const float*)d_in[4];
    const float* W1   = (const float*)d_in[5];
    const float* b1   = (const float*)d_in[6];
    const float* g2   = (const float*)d_in[7];
    const float* be2  = (const float*)d_in[8];
    const float* W2   = (const float*)d_in[9];
    const float* b2   = (const float*)d_in[10];
    float* out = (float*)d_out;

    // workspace layout: ~56 MB
    float* ws      = (float*)d_ws;
    float* nrm     = ws;                                  // N
    int*   deg     = (int*)(ws + N_NODESC);               // N
    int*   cursor  = deg + N_NODESC;                      // N
    int*   rowptr  = cursor + N_NODESC;                   // N+1 (pad to 50016)
    int*   bsums   = rowptr + 50016;                      // 256
    int*   boff    = bsums + 256;                         // 256
    int*   csr     = boff + 256;                          // E
    float* P       = (float*)(csr + N_EDGESC);            // N*D
    float* Q       = P + (size_t)N_NODESC * DDIM;         // N*D
    float* partials = Q + (size_t)N_NODESC * DDIM;        // STAT_BLOCKS*256
    float* mu      = partials + STAT_BLOCKS * 256;        // 128
    float* rstd    = mu + DDIM;                           // 128
    float* W2f     = rstd + DDIM;                         // 128*40
    float* b2f     = W2f + DDIM * NCLASS;                 // 40

    (void)in_sizes; (void)n_in; (void)out_size; (void)ws_size;

    hipMemsetAsync(deg, 0, N_NODESC * sizeof(int), stream);
    deg_kernel<<<(N_EDGESC + 255) / 256, 256, 0, stream>>>(dst, deg);
    norm_kernel<<<(N_NODESC + 255) / 256, 256, 0, stream>>>(deg, nrm);
    scan1_kernel<<<STAT_BLOCKS, 256, 0, stream>>>(deg, rowptr, bsums);
    scan2_kernel<<<1, 256, 0, stream>>>(bsums, boff);
    scan3_kernel<<<STAT_BLOCKS, 256, 0, stream>>>(rowptr, boff, cursor);
    fill_kernel<<<(N_EDGESC + 255) / 256, 256, 0, stream>>>(src, dst, cursor, csr);
    sortrows_kernel<<<STAT_BLOCKS, 256, 0, stream>>>(rowptr, csr);

    // layer 0: P = nrm * S(nrm * h)
    gather_kernel<false><<<GATHER_BLOCKS, 256, 0, stream>>>(h, nrm, rowptr, csr,
                                                            nullptr, nullptr, nullptr, nullptr, P);
    stats_kernel<<<STAT_BLOCKS, 256, 0, stream>>>(P, partials);
    finalize_kernel<<<1, 128, 0, stream>>>(partials, mu, rstd);
    // layer 1: Q = nrm * S(nrm * relu(BN(P)))
    gather_kernel<true><<<GATHER_BLOCKS, 256, 0, stream>>>(P, nrm, rowptr, csr,
                                                           mu, rstd, bn_g, bn_b, Q);
    stats_kernel<<<STAT_BLOCKS, 256, 0, stream>>>(Q, partials);
    finalize_kernel<<<1, 128, 0, stream>>>(partials, mu, rstd);
    // layer 2
    gather_kernel<true><<<GATHER_BLOCKS, 256, 0, stream>>>(Q, nrm, rowptr, csr,
                                                           mu, rstd, bn_g, bn_b, P);
    stats_kernel<<<STAT_BLOCKS, 256, 0, stream>>>(P, partials);
    finalize_kernel<<<1, 128, 0, stream>>>(partials, mu, rstd);
    // layer 3
    gather_kernel<true><<<GATHER_BLOCKS, 256, 0, stream>>>(P, nrm, rowptr, csr,
                                                           mu, rstd, bn_g, bn_b, Q);
    stats_kernel<<<STAT_BLOCKS, 256, 0, stream>>>(Q, partials);
    finalize_kernel<<<1, 128, 0, stream>>>(partials, mu, rstd);

    // epilogue: X(P) = relu(BN(Q)) @ W1 + b1 ; BN2 folded into W2 ; out = X @ W2f + b2f
    linear1_kernel<<<512, 256, 0, stream>>>(Q, W1, b1, mu, rstd, bn_g, bn_b, P);
    stats_kernel<<<STAT_BLOCKS, 256, 0, stream>>>(P, partials);
    finalize_kernel<<<1, 128, 0, stream>>>(partials, mu, rstd);
    fold_kernel<<<1, 256, 0, stream>>>(W2, b2, g2, be2, mu, rstd, W2f, b2f);
    linear2_kernel<<<512, 256, 0, stream>>>(P, W2f, b2f, out);
}

// Round 4
// 457.465 us; speedup vs baseline: 9.5403x; 1.4153x over previous
//
#include <hip/hip_runtime.h>

#define N_NODESC 50000
#define N_EDGESC 600000
#define DDIM 128
#define NCLASS 40
#define BN_EPS 1e-5f
#define STAT_BLOCKS 196     // ceil(50000/256)
#define GATHER_BLOCKS 2048

typedef short bhalf8 __attribute__((ext_vector_type(8)));
typedef float f32x4 __attribute__((ext_vector_type(4)));

union ABfrag { bhalf8 v; unsigned short u[8]; uint4 q; };

__device__ inline float bflo(unsigned d) { return __builtin_bit_cast(float, d << 16); }
__device__ inline float bfhi(unsigned d) { return __builtin_bit_cast(float, d & 0xffff0000u); }
__device__ inline unsigned short f2bf(float f) {
    unsigned u = __builtin_bit_cast(unsigned, f);
    u += 0x7fffu + ((u >> 16) & 1u);        // RNE
    return (unsigned short)(u >> 16);
}

// ---------------- degree / norm ----------------
__global__ __launch_bounds__(256) void deg_kernel(const int* __restrict__ dst, int* __restrict__ deg) {
    int e = blockIdx.x * 256 + threadIdx.x;
    if (e < N_EDGESC) atomicAdd(&deg[dst[e]], 1);
}

__global__ __launch_bounds__(256) void norm_kernel(const int* __restrict__ deg, float* __restrict__ nrm) {
    int i = blockIdx.x * 256 + threadIdx.x;
    if (i < N_NODESC) {
        float d = (float)deg[i];
        nrm[i] = rsqrtf(fmaxf(d, 1.0f));
    }
}

// ---------------- hierarchical exclusive scan: deg -> rowptr ----------------
__global__ __launch_bounds__(256) void scan1_kernel(const int* __restrict__ deg,
                                                    int* __restrict__ rowptr,
                                                    int* __restrict__ blocksums) {
    __shared__ int sh[256];
    int t = threadIdx.x;
    int i = blockIdx.x * 256 + t;
    int v = (i < N_NODESC) ? deg[i] : 0;
    sh[t] = v;
    __syncthreads();
    #pragma unroll
    for (int off = 1; off < 256; off <<= 1) {
        int tv = (t >= off) ? sh[t - off] : 0;
        __syncthreads();
        sh[t] += tv;
        __syncthreads();
    }
    if (i < N_NODESC) rowptr[i] = sh[t] - v;
    if (t == 255) blocksums[blockIdx.x] = sh[255];
}

__global__ void scan2_kernel(const int* __restrict__ blocksums, int* __restrict__ blockoff) {
    __shared__ int sh[256];
    int t = threadIdx.x;
    int v = (t < STAT_BLOCKS) ? blocksums[t] : 0;
    sh[t] = v;
    __syncthreads();
    #pragma unroll
    for (int off = 1; off < 256; off <<= 1) {
        int tv = (t >= off) ? sh[t - off] : 0;
        __syncthreads();
        sh[t] += tv;
        __syncthreads();
    }
    blockoff[t] = sh[t] - v;
}

__global__ __launch_bounds__(256) void scan3_kernel(int* __restrict__ rowptr,
                                                    const int* __restrict__ blockoff,
                                                    int* __restrict__ cursor) {
    int i = blockIdx.x * 256 + threadIdx.x;
    if (i < N_NODESC) {
        int r = rowptr[i] + blockoff[blockIdx.x];
        rowptr[i] = r;
        cursor[i] = r;
    }
    if (blockIdx.x == 0 && threadIdx.x == 0) rowptr[N_NODESC] = N_EDGESC;
}

// ---------------- CSR fill + per-row sort (deterministic order) ----------------
__global__ __launch_bounds__(256) void fill_kernel(const int* __restrict__ src,
                                                   const int* __restrict__ dst,
                                                   int* __restrict__ cursor,
                                                   int* __restrict__ csr) {
    int e = blockIdx.x * 256 + threadIdx.x;
    if (e < N_EDGESC) {
        int d = dst[e];
        int p = atomicAdd(&cursor[d], 1);
        csr[p] = src[e];
    }
}

__global__ __launch_bounds__(256) void sortrows_kernel(const int* __restrict__ rowptr,
                                                       int* __restrict__ csr) {
    int i = blockIdx.x * 256 + threadIdx.x;
    if (i >= N_NODESC) return;
    int b = rowptr[i], e = rowptr[i + 1];
    for (int j = b + 1; j < e; j++) {
        int v = csr[j];
        int k = j - 1;
        while (k >= b && csr[k] > v) { csr[k + 1] = csr[k]; k--; }
        csr[k + 1] = v;
    }
}

// ---------------- h -> bf16 ----------------
__global__ __launch_bounds__(256) void hconv_kernel(const float* __restrict__ h,
                                                    unsigned short* __restrict__ out) {
    int i = blockIdx.x * 256 + threadIdx.x;   // one uint4 (8 bf16) each
    if (i < N_NODESC * DDIM / 8) {
        float4 v0 = reinterpret_cast<const float4*>(h)[i * 2];
        float4 v1 = reinterpret_cast<const float4*>(h)[i * 2 + 1];
        uint4 p;
        p.x = (unsigned)f2bf(v0.x) | ((unsigned)f2bf(v0.y) << 16);
        p.y = (unsigned)f2bf(v0.z) | ((unsigned)f2bf(v0.w) << 16);
        p.z = (unsigned)f2bf(v1.x) | ((unsigned)f2bf(v1.y) << 16);
        p.w = (unsigned)f2bf(v1.z) | ((unsigned)f2bf(v1.w) << 16);
        reinterpret_cast<uint4*>(out)[i] = p;
    }
}

// ---------------- W1 -> bf16 transposed [n][k] ----------------
__global__ __launch_bounds__(256) void w1prep_kernel(const float* __restrict__ W1,
                                                     unsigned short* __restrict__ W1T) {
    int idx = blockIdx.x * 256 + threadIdx.x;   // 16384
    if (idx < DDIM * DDIM) {
        int k = idx >> 7, n = idx & 127;        // coalesced read of W1[k][n]
        W1T[n * DDIM + k] = f2bf(W1[idx]);
    }
}

// ---------------- gather (bf16 in/out) with fused BN+ReLU of the PREVIOUS layer ----------------
// out[i] = bf16( nrm[i] * sum_{s in row i} nrm[s] * act(in[s]) )
template <bool BN>
__global__ __launch_bounds__(256) void gather_kernel(const unsigned short* __restrict__ in,
                                                     const float* __restrict__ nrm,
                                                     const int* __restrict__ rowptr,
                                                     const int* __restrict__ csr,
                                                     const float* __restrict__ mu,
                                                     const float* __restrict__ rstd,
                                                     const float* __restrict__ gamma,
                                                     const float* __restrict__ beta,
                                                     unsigned short* __restrict__ out) {
    int lane = threadIdx.x & 63;
    int wave = threadIdx.x >> 6;   // 0..3
    int q    = lane >> 4;          // edge slot 0..3
    int c    = lane & 15;          // 8-col group: cols [8c, 8c+8)
    float sc[8], sh[8];
    if (BN) {
        float4 m0 = *reinterpret_cast<const float4*>(mu + c * 8);
        float4 m1 = *reinterpret_cast<const float4*>(mu + c * 8 + 4);
        float4 r0 = *reinterpret_cast<const float4*>(rstd + c * 8);
        float4 r1 = *reinterpret_cast<const float4*>(rstd + c * 8 + 4);
        float4 g0 = *reinterpret_cast<const float4*>(gamma + c * 8);
        float4 g1 = *reinterpret_cast<const float4*>(gamma + c * 8 + 4);
        float4 b0 = *reinterpret_cast<const float4*>(beta + c * 8);
        float4 b1 = *reinterpret_cast<const float4*>(beta + c * 8 + 4);
        sc[0] = r0.x * g0.x; sc[1] = r0.y * g0.y; sc[2] = r0.z * g0.z; sc[3] = r0.w * g0.w;
        sc[4] = r1.x * g1.x; sc[5] = r1.y * g1.y; sc[6] = r1.z * g1.z; sc[7] = r1.w * g1.w;
        sh[0] = b0.x - m0.x * sc[0]; sh[1] = b0.y - m0.y * sc[1];
        sh[2] = b0.z - m0.z * sc[2]; sh[3] = b0.w - m0.w * sc[3];
        sh[4] = b1.x - m1.x * sc[4]; sh[5] = b1.y - m1.y * sc[5];
        sh[6] = b1.z - m1.z * sc[6]; sh[7] = b1.w - m1.w * sc[7];
    }
    for (int i = blockIdx.x * 4 + wave; i < N_NODESC; i += GATHER_BLOCKS * 4) {
        int b = rowptr[i], e = rowptr[i + 1];
        float a[8] = {0.f, 0.f, 0.f, 0.f, 0.f, 0.f, 0.f, 0.f};
        for (int j = b + q; j < e; j += 4) {
            int sidx = csr[j];
            float ns = nrm[sidx];
            uint4 d = reinterpret_cast<const uint4*>(in + (size_t)sidx * DDIM)[c];
            float f[8];
            f[0] = bflo(d.x); f[1] = bfhi(d.x);
            f[2] = bflo(d.y); f[3] = bfhi(d.y);
            f[4] = bflo(d.z); f[5] = bfhi(d.z);
            f[6] = bflo(d.w); f[7] = bfhi(d.w);
            #pragma unroll
            for (int t = 0; t < 8; t++) {
                float v = BN ? fmaxf(f[t] * sc[t] + sh[t], 0.f) : f[t];
                a[t] += v * ns;
            }
        }
        #pragma unroll
        for (int t = 0; t < 8; t++) a[t] += __shfl_xor(a[t], 16);
        #pragma unroll
        for (int t = 0; t < 8; t++) a[t] += __shfl_xor(a[t], 32);
        if (q == 0) {
            float ni = nrm[i];
            uint4 p;
            p.x = (unsigned)f2bf(a[0] * ni) | ((unsigned)f2bf(a[1] * ni) << 16);
            p.y = (unsigned)f2bf(a[2] * ni) | ((unsigned)f2bf(a[3] * ni) << 16);
            p.z = (unsigned)f2bf(a[4] * ni) | ((unsigned)f2bf(a[5] * ni) << 16);
            p.w = (unsigned)f2bf(a[6] * ni) | ((unsigned)f2bf(a[7] * ni) << 16);
            reinterpret_cast<uint4*>(out + (size_t)i * DDIM)[c] = p;
        }
    }
}

// ---------------- BN column stats over bf16 matrix ----------------
__global__ __launch_bounds__(256) void stats_bf16_kernel(const unsigned short* __restrict__ x,
                                                         float* __restrict__ partials) {
    __shared__ float sh[256];
    int c2 = threadIdx.x & 63;   // cols 2c2, 2c2+1
    int rg = threadIdx.x >> 6;   // 0..3
    int row0 = blockIdx.x * 256;
    int rowEnd = row0 + 256; if (rowEnd > N_NODESC) rowEnd = N_NODESC;
    float s0 = 0.f, s1 = 0.f, q0 = 0.f, q1 = 0.f;
    for (int r = row0 + rg; r < rowEnd; r += 4) {
        unsigned d = reinterpret_cast<const unsigned*>(x + (size_t)r * DDIM)[c2];
        float f0 = bflo(d), f1 = bfhi(d);
        s0 += f0; q0 += f0 * f0;
        s1 += f1; q1 += f1 * f1;
    }
    sh[threadIdx.x] = s0; __syncthreads();
    if (rg == 0) s0 += sh[64 + c2] + sh[128 + c2] + sh[192 + c2];
    __syncthreads();
    sh[threadIdx.x] = s1; __syncthreads();
    if (rg == 0) s1 += sh[64 + c2] + sh[128 + c2] + sh[192 + c2];
    __syncthreads();
    sh[threadIdx.x] = q0; __syncthreads();
    if (rg == 0) q0 += sh[64 + c2] + sh[128 + c2] + sh[192 + c2];
    __syncthreads();
    sh[threadIdx.x] = q1; __syncthreads();
    if (rg == 0) {
        q1 += sh[64 + c2] + sh[128 + c2] + sh[192 + c2];
        partials[blockIdx.x * 256 + 2 * c2]           = s0;
        partials[blockIdx.x * 256 + 2 * c2 + 1]       = s1;
        partials[blockIdx.x * 256 + 128 + 2 * c2]     = q0;
        partials[blockIdx.x * 256 + 128 + 2 * c2 + 1] = q1;
    }
}

// ---------------- BN column stats over fp32 matrix (GEMM1 output) ----------------
__global__ __launch_bounds__(256) void stats_f32_kernel(const float* __restrict__ x,
                                                        float* __restrict__ partials) {
    __shared__ float sh[256];
    int col = threadIdx.x & 127;
    int grp = threadIdx.x >> 7;
    int rowEnd = (blockIdx.x + 1) * 256;
    if (rowEnd > N_NODESC) rowEnd = N_NODESC;
    float s = 0.f, q = 0.f;
    for (int r = blockIdx.x * 256 + grp; r < rowEnd; r += 2) {
        float v = x[(size_t)r * DDIM + col];
        s += v;
        q += v * v;
    }
    sh[threadIdx.x] = s;
    __syncthreads();
    float s2 = (grp == 0) ? (s + sh[128 + col]) : 0.f;
    __syncthreads();
    sh[threadIdx.x] = q;
    __syncthreads();
    if (grp == 0) {
        float q2 = q + sh[128 + col];
        partials[blockIdx.x * 256 + col]       = s2;
        partials[blockIdx.x * 256 + 128 + col] = q2;
    }
}

// ---------------- finalize: parallel deterministic reduction (8 slices/col) ----------------
__global__ __launch_bounds__(1024) void finalize_kernel(const float* __restrict__ partials,
                                                        float* __restrict__ mu, float* __restrict__ rstd) {
    __shared__ double shd[2048];
    int col = threadIdx.x & 127;
    int sl  = threadIdx.x >> 7;   // 0..7
    double s = 0.0, q = 0.0;
    for (int b = sl; b < STAT_BLOCKS; b += 8) {
        s += (double)partials[b * 256 + col];
        q += (double)partials[b * 256 + 128 + col];
    }
    shd[threadIdx.x] = s;
    shd[1024 + threadIdx.x] = q;
    __syncthreads();
    if (sl == 0) {
        #pragma unroll
        for (int k = 1; k < 8; k++) {
            s += shd[k * 128 + col];
            q += shd[1024 + k * 128 + col];
        }
        double m = s / (double)N_NODESC;
        double v = q / (double)N_NODESC - m * m;
        if (v < 0.0) v = 0.0;
        mu[col]   = (float)m;
        rstd[col] = rsqrtf((float)v + BN_EPS);
    }
}

// ---------------- GEMM1 (MFMA): X = relu(BN(Q_bf16)) @ W1 + b1, fp32 out ----------------
// block = 4 waves; each wave: one 16-row x 128-col tile; 782 blocks cover 3128 tiles >= 3125
__global__ __launch_bounds__(256) void linear1_mfma(const unsigned short* __restrict__ Qb,
                                                    const unsigned short* __restrict__ W1T,
                                                    const float* __restrict__ b1,
                                                    const float* __restrict__ mu,
                                                    const float* __restrict__ rstd,
                                                    const float* __restrict__ gamma,
                                                    const float* __restrict__ beta,
                                                    float* __restrict__ X) {
    __shared__ uint4 wlds[2048];               // 32 KB: W1T bf16 [n][k], XOR-swizzled
    __shared__ float scs[DDIM], shs[DDIM], bias[DDIM];
    int tid = threadIdx.x;
    for (int i = tid; i < 2048; i += 256) {
        uint4 v = reinterpret_cast<const uint4*>(W1T)[i];
        int o = i << 4;                        // byte offset
        int n = o >> 8;                        // row n (256 B each)
        int sw = (o & 255) ^ ((n & 7) << 4);   // swizzle 16B chunk within the row
        wlds[(n << 4) | (sw >> 4)] = v;
    }
    if (tid < DDIM) {
        float a = rstd[tid] * gamma[tid];
        scs[tid] = a;
        shs[tid] = beta[tid] - mu[tid] * a;
        bias[tid] = b1[tid];
    }
    __syncthreads();
    int wave = tid >> 6, lane = tid & 63;
    int l15 = lane & 15, l4 = lane >> 4;
    int tile = blockIdx.x * 4 + wave;
    if (tile >= 3128) return;
    int row0 = tile * 16;
    int arow = row0 + l15; if (arow >= N_NODESC) arow = N_NODESC - 1;
    const uint4* aptr = reinterpret_cast<const uint4*>(Qb + (size_t)arow * DDIM);
    f32x4 acc[8];
    #pragma unroll
    for (int cf = 0; cf < 8; cf++) acc[cf] = (f32x4){0.f, 0.f, 0.f, 0.f};
    #pragma unroll
    for (int ks = 0; ks < 4; ks++) {
        uint4 ad = aptr[ks * 4 + l4];          // 16 B = 8 bf16 at k = ks*32 + l4*8
        int kb = ks * 32 + l4 * 8;
        ABfrag a;
        float f;
        f = bflo(ad.x); a.u[0] = f2bf(fmaxf(f * scs[kb + 0] + shs[kb + 0], 0.f));
        f = bfhi(ad.x); a.u[1] = f2bf(fmaxf(f * scs[kb + 1] + shs[kb + 1], 0.f));
        f = bflo(ad.y); a.u[2] = f2bf(fmaxf(f * scs[kb + 2] + shs[kb + 2], 0.f));
        f = bfhi(ad.y); a.u[3] = f2bf(fmaxf(f * scs[kb + 3] + shs[kb + 3], 0.f));
        f = bflo(ad.z); a.u[4] = f2bf(fmaxf(f * scs[kb + 4] + shs[kb + 4], 0.f));
        f = bfhi(ad.z); a.u[5] = f2bf(fmaxf(f * scs[kb + 5] + shs[kb + 5], 0.f));
        f = bflo(ad.w); a.u[6] = f2bf(fmaxf(f * scs[kb + 6] + shs[kb + 6], 0.f));
        f = bfhi(ad.w); a.u[7] = f2bf(fmaxf(f * scs[kb + 7] + shs[kb + 7], 0.f));
        int koff = ks * 64 + l4 * 16;          // byte offset within W1T row
        #pragma unroll
        for (int cf = 0; cf < 8; cf++) {
            int n = cf * 16 + l15;
            ABfrag b;
            b.q = wlds[(n << 4) | ((koff ^ ((n & 7) << 4)) >> 4)];
            acc[cf] = __builtin_amdgcn_mfma_f32_16x16x32_bf16(a.v, b.v, acc[cf], 0, 0, 0);
        }
    }
    #pragma unroll
    for (int cf = 0; cf < 8; cf++) {
        int col = cf * 16 + l15;
        float bb = bias[col];
        #pragma unroll
        for (int r = 0; r < 4; r++) {
            int row = row0 + l4 * 4 + r;
            if (row < N_NODESC) X[(size_t)row * DDIM + col] = acc[cf][r] + bb;
        }
    }
}

// ---------------- fold BN2 into W2/b2 ----------------
__global__ void fold_kernel(const float* __restrict__ W2, const float* __restrict__ b2,
                            const float* __restrict__ g2, const float* __restrict__ be2,
                            const float* __restrict__ mu2, const float* __restrict__ rstd2,
                            float* __restrict__ W2f, float* __restrict__ b2f) {
    __shared__ float s[DDIM], t[DDIM];
    int tid = threadIdx.x;  // 256
    if (tid < DDIM) {
        float sc = rstd2[tid] * g2[tid];
        s[tid] = sc;
        t[tid] = be2[tid] - mu2[tid] * sc;
    }
    __syncthreads();
    for (int idx = tid; idx < DDIM * NCLASS; idx += 256) {
        int k = idx / NCLASS;
        W2f[idx] = W2[idx] * s[k];
    }
    if (tid < NCLASS) {
        float acc = b2[tid];
        for (int k = 0; k < DDIM; k++) acc += t[k] * W2[k * NCLASS + tid];
        b2f[tid] = acc;
    }
}

// ---------------- GEMM2: out = X @ W2f + b2f ----------------
#define L2_TILE 64
__global__ __launch_bounds__(256) void linear2_kernel(const float* __restrict__ X,
                                                      const float* __restrict__ W2f,
                                                      const float* __restrict__ b2f,
                                                      float* __restrict__ out) {
    __shared__ float Ws[DDIM][NCLASS];  // 20 KB
    for (int idx = threadIdx.x; idx < DDIM * NCLASS; idx += 256) {
        (&Ws[0][0])[idx] = W2f[idx];
    }
    __syncthreads();
    int cg = threadIdx.x & 7;    // cols [5cg, 5cg+5)
    int rp = threadIdx.x >> 3;   // rows rp*2, rp*2+1
    int c0 = cg * 5;
    for (int base = blockIdx.x * L2_TILE; base < N_NODESC; base += gridDim.x * L2_TILE) {
        int row0 = base + rp * 2;
        int row1 = row0 + 1;
        int r0c = row0 < N_NODESC ? row0 : (N_NODESC - 1);
        int r1c = row1 < N_NODESC ? row1 : (N_NODESC - 1);
        const float* r0p = X + (size_t)r0c * DDIM;
        const float* r1p = X + (size_t)r1c * DDIM;
        float a0[5] = {0.f, 0.f, 0.f, 0.f, 0.f};
        float a1[5] = {0.f, 0.f, 0.f, 0.f, 0.f};
        #pragma unroll 4
        for (int k4 = 0; k4 < DDIM; k4 += 4) {
            float4 x0 = *reinterpret_cast<const float4*>(r0p + k4);
            float4 x1 = *reinterpret_cast<const float4*>(r1p + k4);
            #pragma unroll
            for (int j = 0; j < 5; j++) {
                float w0 = Ws[k4 + 0][c0 + j];
                float w1 = Ws[k4 + 1][c0 + j];
                float w2 = Ws[k4 + 2][c0 + j];
                float w3 = Ws[k4 + 3][c0 + j];
                a0[j] += w0 * x0.x + w1 * x0.y + w2 * x0.z + w3 * x0.w;
                a1[j] += w0 * x1.x + w1 * x1.y + w2 * x1.z + w3 * x1.w;
            }
        }
        if (row0 < N_NODESC) {
            #pragma unroll
            for (int j = 0; j < 5; j++) out[(size_t)row0 * NCLASS + c0 + j] = a0[j] + b2f[c0 + j];
        }
        if (row1 < N_NODESC) {
            #pragma unroll
            for (int j = 0; j < 5; j++) out[(size_t)row1 * NCLASS + c0 + j] = a1[j] + b2f[c0 + j];
        }
    }
}

extern "C" void kernel_launch(void* const* d_in, const int* in_sizes, int n_in,
                              void* d_out, int out_size, void* d_ws, size_t ws_size,
                              hipStream_t stream) {
    const float* h    = (const float*)d_in[0];
    const int*   src  = (const int*)d_in[1];
    const int*   dst  = (const int*)d_in[2];
    const float* bn_g = (const float*)d_in[3];
    const float* bn_b = (const float*)d_in[4];
    const float* W1   = (const float*)d_in[5];
    const float* b1   = (const float*)d_in[6];
    const float* g2   = (const float*)d_in[7];
    const float* be2  = (const float*)d_in[8];
    const float* W2   = (const float*)d_in[9];
    const float* b2   = (const float*)d_in[10];
    float* out = (float*)d_out;

    // workspace layout (floats; ~55 MB total)
    float* ws      = (float*)d_ws;
    float* nrm     = ws;                                   // 50000
    int*   deg     = (int*)(ws + N_NODESC);                // 50000
    int*   cursor  = deg + N_NODESC;                       // 50000
    int*   rowptr  = cursor + N_NODESC;                    // pad 50016
    int*   bsums   = rowptr + 50016;                       // 256
    int*   boff    = bsums + 256;                          // 256
    int*   csr     = boff + 256;                           // 600000
    float* partials = (float*)(csr + N_EDGESC);            // 196*256 = 50176
    float* mu      = partials + STAT_BLOCKS * 256;         // 128
    float* rstd    = mu + DDIM;                            // 128
    float* W2f     = rstd + DDIM;                          // 5120
    float* b2f     = W2f + DDIM * NCLASS;                  // pad 64
    unsigned short* W1T = (unsigned short*)(b2f + 64);     // 16384 ushort (8192 f)
    unsigned short* Hb  = (unsigned short*)((float*)W1T + 8192);   // 6.4M ushort (3.2M f)
    unsigned short* Pb  = (unsigned short*)((float*)Hb + 3200000); // 6.4M ushort
    float* X       = (float*)((float*)Pb + 3200000);       // 6.4M floats

    (void)in_sizes; (void)n_in; (void)out_size; (void)ws_size;

    hipMemsetAsync(deg, 0, N_NODESC * sizeof(int), stream);
    deg_kernel<<<(N_EDGESC + 255) / 256, 256, 0, stream>>>(dst, deg);
    norm_kernel<<<(N_NODESC + 255) / 256, 256, 0, stream>>>(deg, nrm);
    scan1_kernel<<<STAT_BLOCKS, 256, 0, stream>>>(deg, rowptr, bsums);
    scan2_kernel<<<1, 256, 0, stream>>>(bsums, boff);
    scan3_kernel<<<STAT_BLOCKS, 256, 0, stream>>>(rowptr, boff, cursor);
    fill_kernel<<<(N_EDGESC + 255) / 256, 256, 0, stream>>>(src, dst, cursor, csr);
    sortrows_kernel<<<STAT_BLOCKS, 256, 0, stream>>>(rowptr, csr);
    hconv_kernel<<<(N_NODESC * DDIM / 8 + 255) / 256, 256, 0, stream>>>(h, Hb);
    w1prep_kernel<<<(DDIM * DDIM + 255) / 256, 256, 0, stream>>>(W1, W1T);

    // layer 0: Pb = nrm * S(nrm * Hb)
    gather_kernel<false><<<GATHER_BLOCKS, 256, 0, stream>>>(Hb, nrm, rowptr, csr,
                                                            nullptr, nullptr, nullptr, nullptr, Pb);
    stats_bf16_kernel<<<STAT_BLOCKS, 256, 0, stream>>>(Pb, partials);
    finalize_kernel<<<1, 1024, 0, stream>>>(partials, mu, rstd);
    // layer 1: Hb = nrm * S(nrm * relu(BN(Pb)))
    gather_kernel<true><<<GATHER_BLOCKS, 256, 0, stream>>>(Pb, nrm, rowptr, csr,
                                                           mu, rstd, bn_g, bn_b, Hb);
    stats_bf16_kernel<<<STAT_BLOCKS, 256, 0, stream>>>(Hb, partials);
    finalize_kernel<<<1, 1024, 0, stream>>>(partials, mu, rstd);
    // layer 2
    gather_kernel<true><<<GATHER_BLOCKS, 256, 0, stream>>>(Hb, nrm, rowptr, csr,
                                                           mu, rstd, bn_g, bn_b, Pb);
    stats_bf16_kernel<<<STAT_BLOCKS, 256, 0, stream>>>(Pb, partials);
    finalize_kernel<<<1, 1024, 0, stream>>>(partials, mu, rstd);
    // layer 3
    gather_kernel<true><<<GATHER_BLOCKS, 256, 0, stream>>>(Pb, nrm, rowptr, csr,
                                                           mu, rstd, bn_g, bn_b, Hb);
    stats_bf16_kernel<<<STAT_BLOCKS, 256, 0, stream>>>(Hb, partials);
    finalize_kernel<<<1, 1024, 0, stream>>>(partials, mu, rstd);

    // epilogue: X = relu(BN(Hb)) @ W1 + b1 (MFMA); BN2 folded into W2; out = X @ W2f + b2f
    linear1_mfma<<<782, 256, 0, stream>>>(Hb, W1T, b1, mu, rstd, bn_g, bn_b, X);
    stats_f32_kernel<<<STAT_BLOCKS, 256, 0, stream>>>(X, partials);
    finalize_kernel<<<1, 1024, 0, stream>>>(partials, mu, rstd);
    fold_kernel<<<1, 256, 0, stream>>>(W2, b2, g2, be2, mu, rstd, W2f, b2f);
    linear2_kernel<<<512, 256, 0, stream>>>(X, W2f, b2f, out);
}

// Round 5
// 429.430 us; speedup vs baseline: 10.1632x; 1.0653x over previous
//
#include <hip/hip_runtime.h>

#define N_NODESC 50000
#define N_EDGESC 600000
#define DDIM 128
#define NCLASS 40
#define BN_EPS 1e-5f
#define STAT_BLOCKS 196     // ceil(50000/256)
#define GATHER_BLOCKS 2048
#define SORT_ROWS 128
#define SORT_CAP 2560       // 10 KB; avg block load ~1530 edges, +20 sigma safe
#define SORT_BLOCKS 391     // ceil(50000/128)

typedef short bhalf8 __attribute__((ext_vector_type(8)));
typedef float f32x4 __attribute__((ext_vector_type(4)));

union ABfrag { bhalf8 v; unsigned short u[8]; uint4 q; };

__device__ inline float bflo(unsigned d) { return __builtin_bit_cast(float, d << 16); }
__device__ inline float bfhi(unsigned d) { return __builtin_bit_cast(float, d & 0xffff0000u); }
__device__ inline unsigned short f2bf(float f) {
    unsigned u = __builtin_bit_cast(unsigned, f);
    u += 0x7fffu + ((u >> 16) & 1u);        // RNE
    return (unsigned short)(u >> 16);
}

// ---------------- degree ----------------
__global__ __launch_bounds__(256) void deg_kernel(const int* __restrict__ dst, int* __restrict__ deg) {
    int e = blockIdx.x * 256 + threadIdx.x;
    if (e < N_EDGESC) atomicAdd(&deg[dst[e]], 1);
}

// ---------------- hierarchical exclusive scan: deg -> rowptr (+ nrm fused in stage 3) ----------------
__global__ __launch_bounds__(256) void scan1_kernel(const int* __restrict__ deg,
                                                    int* __restrict__ rowptr,
                                                    int* __restrict__ blocksums) {
    __shared__ int sh[256];
    int t = threadIdx.x;
    int i = blockIdx.x * 256 + t;
    int v = (i < N_NODESC) ? deg[i] : 0;
    sh[t] = v;
    __syncthreads();
    #pragma unroll
    for (int off = 1; off < 256; off <<= 1) {
        int tv = (t >= off) ? sh[t - off] : 0;
        __syncthreads();
        sh[t] += tv;
        __syncthreads();
    }
    if (i < N_NODESC) rowptr[i] = sh[t] - v;
    if (t == 255) blocksums[blockIdx.x] = sh[255];
}

__global__ void scan2_kernel(const int* __restrict__ blocksums, int* __restrict__ blockoff) {
    __shared__ int sh[256];
    int t = threadIdx.x;
    int v = (t < STAT_BLOCKS) ? blocksums[t] : 0;
    sh[t] = v;
    __syncthreads();
    #pragma unroll
    for (int off = 1; off < 256; off <<= 1) {
        int tv = (t >= off) ? sh[t - off] : 0;
        __syncthreads();
        sh[t] += tv;
        __syncthreads();
    }
    blockoff[t] = sh[t] - v;
}

__global__ __launch_bounds__(256) void scan3_kernel(int* __restrict__ rowptr,
                                                    const int* __restrict__ blockoff,
                                                    const int* __restrict__ deg,
                                                    int* __restrict__ cursor,
                                                    float* __restrict__ nrm) {
    int i = blockIdx.x * 256 + threadIdx.x;
    if (i < N_NODESC) {
        int r = rowptr[i] + blockoff[blockIdx.x];
        rowptr[i] = r;
        cursor[i] = r;
        nrm[i] = rsqrtf(fmaxf((float)deg[i], 1.0f));
    }
    if (blockIdx.x == 0 && threadIdx.x == 0) rowptr[N_NODESC] = N_EDGESC;
}

// ---------------- CSR fill (order nondeterministic, fixed by sort) ----------------
__global__ __launch_bounds__(256) void fill_kernel(const int* __restrict__ src,
                                                   const int* __restrict__ dst,
                                                   int* __restrict__ cursor,
                                                   int* __restrict__ csr) {
    int e = blockIdx.x * 256 + threadIdx.x;
    if (e < N_EDGESC) {
        int d = dst[e];
        int p = atomicAdd(&cursor[d], 1);
        csr[p] = src[e];
    }
}

// ---------------- per-row sort in LDS -> deterministic edge order ----------------
__global__ __launch_bounds__(128) void sortrows_kernel(const int* __restrict__ rowptr,
                                                       int* __restrict__ csr) {
    __shared__ int buf[SORT_CAP];
    int r0 = blockIdx.x * SORT_ROWS;
    int r1 = r0 + SORT_ROWS; if (r1 > N_NODESC) r1 = N_NODESC;
    int base = rowptr[r0];
    int end  = rowptr[r1];
    int cnt  = end - base;
    if (cnt <= SORT_CAP) {
        for (int j = threadIdx.x; j < cnt; j += 128) buf[j] = csr[base + j];
        __syncthreads();
        int i = r0 + threadIdx.x;
        if (i < r1) {
            int b = rowptr[i] - base, e = rowptr[i + 1] - base;
            for (int j = b + 1; j < e; j++) {
                int v = buf[j];
                int k = j - 1;
                while (k >= b && buf[k] > v) { buf[k + 1] = buf[k]; k--; }
                buf[k + 1] = v;
            }
        }
        __syncthreads();
        for (int j = threadIdx.x; j < cnt; j += 128) csr[base + j] = buf[j];
    } else {
        // never expected; correctness fallback in global memory
        int i = r0 + threadIdx.x;
        if (i < r1) {
            int b = rowptr[i], e = rowptr[i + 1];
            for (int j = b + 1; j < e; j++) {
                int v = csr[j];
                int k = j - 1;
                while (k >= b && csr[k] > v) { csr[k + 1] = csr[k]; k--; }
                csr[k + 1] = v;
            }
        }
    }
}

// ---------------- h -> bf16 ----------------
__global__ __launch_bounds__(256) void hconv_kernel(const float* __restrict__ h,
                                                    unsigned short* __restrict__ out) {
    int i = blockIdx.x * 256 + threadIdx.x;   // one uint4 (8 bf16) each
    if (i < N_NODESC * DDIM / 8) {
        float4 v0 = reinterpret_cast<const float4*>(h)[i * 2];
        float4 v1 = reinterpret_cast<const float4*>(h)[i * 2 + 1];
        uint4 p;
        p.x = (unsigned)f2bf(v0.x) | ((unsigned)f2bf(v0.y) << 16);
        p.y = (unsigned)f2bf(v0.z) | ((unsigned)f2bf(v0.w) << 16);
        p.z = (unsigned)f2bf(v1.x) | ((unsigned)f2bf(v1.y) << 16);
        p.w = (unsigned)f2bf(v1.z) | ((unsigned)f2bf(v1.w) << 16);
        reinterpret_cast<uint4*>(out)[i] = p;
    }
}

// ---------------- W1 -> bf16 transposed [n][k] ----------------
__global__ __launch_bounds__(256) void w1prep_kernel(const float* __restrict__ W1,
                                                     unsigned short* __restrict__ W1T) {
    int idx = blockIdx.x * 256 + threadIdx.x;   // 16384
    if (idx < DDIM * DDIM) {
        int k = idx >> 7, n = idx & 127;        // coalesced read of W1[k][n]
        W1T[n * DDIM + k] = f2bf(W1[idx]);
    }
}

// ---------------- gather (bf16 in/out), fused BN+ReLU of PREVIOUS layer, 1-deep pipelined ----------------
// out[i] = bf16( nrm[i] * sum_{s in row i} nrm[s] * act(in[s]) )
template <bool BN>
__global__ __launch_bounds__(256) void gather_kernel(const unsigned short* __restrict__ in,
                                                     const float* __restrict__ nrm,
                                                     const int* __restrict__ rowptr,
                                                     const int* __restrict__ csr,
                                                     const float* __restrict__ mu,
                                                     const float* __restrict__ rstd,
                                                     const float* __restrict__ gamma,
                                                     const float* __restrict__ beta,
                                                     unsigned short* __restrict__ out) {
    int lane = threadIdx.x & 63;
    int wave = threadIdx.x >> 6;   // 0..3
    int q    = lane >> 4;          // edge slot 0..3
    int c    = lane & 15;          // 8-col group: cols [8c, 8c+8)
    float sc[8], sh[8];
    if (BN) {
        float4 m0 = *reinterpret_cast<const float4*>(mu + c * 8);
        float4 m1 = *reinterpret_cast<const float4*>(mu + c * 8 + 4);
        float4 r0 = *reinterpret_cast<const float4*>(rstd + c * 8);
        float4 r1 = *reinterpret_cast<const float4*>(rstd + c * 8 + 4);
        float4 g0 = *reinterpret_cast<const float4*>(gamma + c * 8);
        float4 g1 = *reinterpret_cast<const float4*>(gamma + c * 8 + 4);
        float4 b0 = *reinterpret_cast<const float4*>(beta + c * 8);
        float4 b1 = *reinterpret_cast<const float4*>(beta + c * 8 + 4);
        sc[0] = r0.x * g0.x; sc[1] = r0.y * g0.y; sc[2] = r0.z * g0.z; sc[3] = r0.w * g0.w;
        sc[4] = r1.x * g1.x; sc[5] = r1.y * g1.y; sc[6] = r1.z * g1.z; sc[7] = r1.w * g1.w;
        sh[0] = b0.x - m0.x * sc[0]; sh[1] = b0.y - m0.y * sc[1];
        sh[2] = b0.z - m0.z * sc[2]; sh[3] = b0.w - m0.w * sc[3];
        sh[4] = b1.x - m1.x * sc[4]; sh[5] = b1.y - m1.y * sc[5];
        sh[6] = b1.z - m1.z * sc[6]; sh[7] = b1.w - m1.w * sc[7];
    }
    for (int i = blockIdx.x * 4 + wave; i < N_NODESC; i += GATHER_BLOCKS * 4) {
        int b = rowptr[i], e = rowptr[i + 1];
        float a[8] = {0.f, 0.f, 0.f, 0.f, 0.f, 0.f, 0.f, 0.f};
        int j = b + q;
        if (j < e) {
            int sidx = csr[j];
            float ns  = nrm[sidx];
            uint4 d   = reinterpret_cast<const uint4*>(in + (size_t)sidx * DDIM)[c];
            for (j += 4;; j += 4) {
                bool more = (j < e);
                int nsidx = 0; float nns = 0.f;
                uint4 nd = make_uint4(0u, 0u, 0u, 0u);
                if (more) {
                    nsidx = csr[j];
                    nns   = nrm[nsidx];
                    nd    = reinterpret_cast<const uint4*>(in + (size_t)nsidx * DDIM)[c];
                }
                float f[8];
                f[0] = bflo(d.x); f[1] = bfhi(d.x);
                f[2] = bflo(d.y); f[3] = bfhi(d.y);
                f[4] = bflo(d.z); f[5] = bfhi(d.z);
                f[6] = bflo(d.w); f[7] = bfhi(d.w);
                #pragma unroll
                for (int t = 0; t < 8; t++) {
                    float v = BN ? fmaxf(f[t] * sc[t] + sh[t], 0.f) : f[t];
                    a[t] += v * ns;
                }
                if (!more) break;
                d = nd; ns = nns;
            }
        }
        #pragma unroll
        for (int t = 0; t < 8; t++) a[t] += __shfl_xor(a[t], 16);
        #pragma unroll
        for (int t = 0; t < 8; t++) a[t] += __shfl_xor(a[t], 32);
        if (q == 0) {
            float ni = nrm[i];
            uint4 p;
            p.x = (unsigned)f2bf(a[0] * ni) | ((unsigned)f2bf(a[1] * ni) << 16);
            p.y = (unsigned)f2bf(a[2] * ni) | ((unsigned)f2bf(a[3] * ni) << 16);
            p.z = (unsigned)f2bf(a[4] * ni) | ((unsigned)f2bf(a[5] * ni) << 16);
            p.w = (unsigned)f2bf(a[6] * ni) | ((unsigned)f2bf(a[7] * ni) << 16);
            reinterpret_cast<uint4*>(out + (size_t)i * DDIM)[c] = p;
        }
    }
}

// ---------------- BN column stats over bf16 matrix ----------------
__global__ __launch_bounds__(256) void stats_bf16_kernel(const unsigned short* __restrict__ x,
                                                         float* __restrict__ partials) {
    __shared__ float sh[256];
    int c2 = threadIdx.x & 63;   // cols 2c2, 2c2+1
    int rg = threadIdx.x >> 6;   // 0..3
    int row0 = blockIdx.x * 256;
    int rowEnd = row0 + 256; if (rowEnd > N_NODESC) rowEnd = N_NODESC;
    float s0 = 0.f, s1 = 0.f, q0 = 0.f, q1 = 0.f;
    for (int r = row0 + rg; r < rowEnd; r += 4) {
        unsigned d = reinterpret_cast<const unsigned*>(x + (size_t)r * DDIM)[c2];
        float f0 = bflo(d), f1 = bfhi(d);
        s0 += f0; q0 += f0 * f0;
        s1 += f1; q1 += f1 * f1;
    }
    sh[threadIdx.x] = s0; __syncthreads();
    if (rg == 0) s0 += sh[64 + c2] + sh[128 + c2] + sh[192 + c2];
    __syncthreads();
    sh[threadIdx.x] = s1; __syncthreads();
    if (rg == 0) s1 += sh[64 + c2] + sh[128 + c2] + sh[192 + c2];
    __syncthreads();
    sh[threadIdx.x] = q0; __syncthreads();
    if (rg == 0) q0 += sh[64 + c2] + sh[128 + c2] + sh[192 + c2];
    __syncthreads();
    sh[threadIdx.x] = q1; __syncthreads();
    if (rg == 0) {
        q1 += sh[64 + c2] + sh[128 + c2] + sh[192 + c2];
        partials[blockIdx.x * 256 + 2 * c2]           = s0;
        partials[blockIdx.x * 256 + 2 * c2 + 1]       = s1;
        partials[blockIdx.x * 256 + 128 + 2 * c2]     = q0;
        partials[blockIdx.x * 256 + 128 + 2 * c2 + 1] = q1;
    }
}

// ---------------- BN column stats over fp32 matrix (GEMM1 output) ----------------
__global__ __launch_bounds__(256) void stats_f32_kernel(const float* __restrict__ x,
                                                        float* __restrict__ partials) {
    __shared__ float sh[256];
    int col = threadIdx.x & 127;
    int grp = threadIdx.x >> 7;
    int rowEnd = (blockIdx.x + 1) * 256;
    if (rowEnd > N_NODESC) rowEnd = N_NODESC;
    float s = 0.f, q = 0.f;
    for (int r = blockIdx.x * 256 + grp; r < rowEnd; r += 2) {
        float v = x[(size_t)r * DDIM + col];
        s += v;
        q += v * v;
    }
    sh[threadIdx.x] = s;
    __syncthreads();
    float s2 = (grp == 0) ? (s + sh[128 + col]) : 0.f;
    __syncthreads();
    sh[threadIdx.x] = q;
    __syncthreads();
    if (grp == 0) {
        float q2 = q + sh[128 + col];
        partials[blockIdx.x * 256 + col]       = s2;
        partials[blockIdx.x * 256 + 128 + col] = q2;
    }
}

// ---------------- finalize: parallel deterministic reduction (8 slices/col) ----------------
__global__ __launch_bounds__(1024) void finalize_kernel(const float* __restrict__ partials,
                                                        float* __restrict__ mu, float* __restrict__ rstd) {
    __shared__ double shd[2048];
    int col = threadIdx.x & 127;
    int sl  = threadIdx.x >> 7;   // 0..7
    double s = 0.0, q = 0.0;
    for (int b = sl; b < STAT_BLOCKS; b += 8) {
        s += (double)partials[b * 256 + col];
        q += (double)partials[b * 256 + 128 + col];
    }
    shd[threadIdx.x] = s;
    shd[1024 + threadIdx.x] = q;
    __syncthreads();
    if (sl == 0) {
        #pragma unroll
        for (int k = 1; k < 8; k++) {
            s += shd[k * 128 + col];
            q += shd[1024 + k * 128 + col];
        }
        double m = s / (double)N_NODESC;
        double v = q / (double)N_NODESC - m * m;
        if (v < 0.0) v = 0.0;
        mu[col]   = (float)m;
        rstd[col] = rsqrtf((float)v + BN_EPS);
    }
}

// ---------------- GEMM1 (MFMA): X = relu(BN(Q_bf16)) @ W1 + b1, fp32 out ----------------
__global__ __launch_bounds__(256) void linear1_mfma(const unsigned short* __restrict__ Qb,
                                                    const unsigned short* __restrict__ W1T,
                                                    const float* __restrict__ b1,
                                                    const float* __restrict__ mu,
                                                    const float* __restrict__ rstd,
                                                    const float* __restrict__ gamma,
                                                    const float* __restrict__ beta,
                                                    float* __restrict__ X) {
    __shared__ uint4 wlds[2048];               // 32 KB: W1T bf16 [n][k], XOR-swizzled
    __shared__ float scs[DDIM], shs[DDIM], bias[DDIM];
    int tid = threadIdx.x;
    for (int i = tid; i < 2048; i += 256) {
        uint4 v = reinterpret_cast<const uint4*>(W1T)[i];
        int o = i << 4;                        // byte offset
        int n = o >> 8;                        // row n (256 B each)
        int sw = (o & 255) ^ ((n & 7) << 4);   // swizzle 16B chunk within the row
        wlds[(n << 4) | (sw >> 4)] = v;
    }
    if (tid < DDIM) {
        float a = rstd[tid] * gamma[tid];
        scs[tid] = a;
        shs[tid] = beta[tid] - mu[tid] * a;
        bias[tid] = b1[tid];
    }
    __syncthreads();
    int wave = tid >> 6, lane = tid & 63;
    int l15 = lane & 15, l4 = lane >> 4;
    int tile = blockIdx.x * 4 + wave;
    if (tile >= 3128) return;
    int row0 = tile * 16;
    int arow = row0 + l15; if (arow >= N_NODESC) arow = N_NODESC - 1;
    const uint4* aptr = reinterpret_cast<const uint4*>(Qb + (size_t)arow * DDIM);
    f32x4 acc[8];
    #pragma unroll
    for (int cf = 0; cf < 8; cf++) acc[cf] = (f32x4){0.f, 0.f, 0.f, 0.f};
    #pragma unroll
    for (int ks = 0; ks < 4; ks++) {
        uint4 ad = aptr[ks * 4 + l4];          // 16 B = 8 bf16 at k = ks*32 + l4*8
        int kb = ks * 32 + l4 * 8;
        ABfrag a;
        float f;
        f = bflo(ad.x); a.u[0] = f2bf(fmaxf(f * scs[kb + 0] + shs[kb + 0], 0.f));
        f = bfhi(ad.x); a.u[1] = f2bf(fmaxf(f * scs[kb + 1] + shs[kb + 1], 0.f));
        f = bflo(ad.y); a.u[2] = f2bf(fmaxf(f * scs[kb + 2] + shs[kb + 2], 0.f));
        f = bfhi(ad.y); a.u[3] = f2bf(fmaxf(f * scs[kb + 3] + shs[kb + 3], 0.f));
        f = bflo(ad.z); a.u[4] = f2bf(fmaxf(f * scs[kb + 4] + shs[kb + 4], 0.f));
        f = bfhi(ad.z); a.u[5] = f2bf(fmaxf(f * scs[kb + 5] + shs[kb + 5], 0.f));
        f = bflo(ad.w); a.u[6] = f2bf(fmaxf(f * scs[kb + 6] + shs[kb + 6], 0.f));
        f = bfhi(ad.w); a.u[7] = f2bf(fmaxf(f * scs[kb + 7] + shs[kb + 7], 0.f));
        int koff = ks * 64 + l4 * 16;          // byte offset within W1T row
        #pragma unroll
        for (int cf = 0; cf < 8; cf++) {
            int n = cf * 16 + l15;
            ABfrag b;
            b.q = wlds[(n << 4) | ((koff ^ ((n & 7) << 4)) >> 4)];
            acc[cf] = __builtin_amdgcn_mfma_f32_16x16x32_bf16(a.v, b.v, acc[cf], 0, 0, 0);
        }
    }
    #pragma unroll
    for (int cf = 0; cf < 8; cf++) {
        int col = cf * 16 + l15;
        float bb = bias[col];
        #pragma unroll
        for (int r = 0; r < 4; r++) {
            int row = row0 + l4 * 4 + r;
            if (row < N_NODESC) X[(size_t)row * DDIM + col] = acc[cf][r] + bb;
        }
    }
}

// ---------------- fold BN2 into W2/b2 ----------------
__global__ void fold_kernel(const float* __restrict__ W2, const float* __restrict__ b2,
                            const float* __restrict__ g2, const float* __restrict__ be2,
                            const float* __restrict__ mu2, const float* __restrict__ rstd2,
                            float* __restrict__ W2f, float* __restrict__ b2f) {
    __shared__ float s[DDIM], t[DDIM];
    int tid = threadIdx.x;  // 256
    if (tid < DDIM) {
        float sc = rstd2[tid] * g2[tid];
        s[tid] = sc;
        t[tid] = be2[tid] - mu2[tid] * sc;
    }
    __syncthreads();
    for (int idx = tid; idx < DDIM * NCLASS; idx += 256) {
        int k = idx / NCLASS;
        W2f[idx] = W2[idx] * s[k];
    }
    if (tid < NCLASS) {
        float acc = b2[tid];
        for (int k = 0; k < DDIM; k++) acc += t[k] * W2[k * NCLASS + tid];
        b2f[tid] = acc;
    }
}

// ---------------- GEMM2: out = X @ W2f + b2f ----------------
#define L2_TILE 64
__global__ __launch_bounds__(256) void linear2_kernel(const float* __restrict__ X,
                                                      const float* __restrict__ W2f,
                                                      const float* __restrict__ b2f,
                                                      float* __restrict__ out) {
    __shared__ float Ws[DDIM][NCLASS];  // 20 KB
    for (int idx = threadIdx.x; idx < DDIM * NCLASS; idx += 256) {
        (&Ws[0][0])[idx] = W2f[idx];
    }
    __syncthreads();
    int cg = threadIdx.x & 7;    // cols [5cg, 5cg+5)
    int rp = threadIdx.x >> 3;   // rows rp*2, rp*2+1
    int c0 = cg * 5;
    for (int base = blockIdx.x * L2_TILE; base < N_NODESC; base += gridDim.x * L2_TILE) {
        int row0 = base + rp * 2;
        int row1 = row0 + 1;
        int r0c = row0 < N_NODESC ? row0 : (N_NODESC - 1);
        int r1c = row1 < N_NODESC ? row1 : (N_NODESC - 1);
        const float* r0p = X + (size_t)r0c * DDIM;
        const float* r1p = X + (size_t)r1c * DDIM;
        float a0[5] = {0.f, 0.f, 0.f, 0.f, 0.f};
        float a1[5] = {0.f, 0.f, 0.f, 0.f, 0.f};
        #pragma unroll 4
        for (int k4 = 0; k4 < DDIM; k4 += 4) {
            float4 x0 = *reinterpret_cast<const float4*>(r0p + k4);
            float4 x1 = *reinterpret_cast<const float4*>(r1p + k4);
            #pragma unroll
            for (int j = 0; j < 5; j++) {
                float w0 = Ws[k4 + 0][c0 + j];
                float w1 = Ws[k4 + 1][c0 + j];
                float w2 = Ws[k4 + 2][c0 + j];
                float w3 = Ws[k4 + 3][c0 + j];
                a0[j] += w0 * x0.x + w1 * x0.y + w2 * x0.z + w3 * x0.w;
                a1[j] += w0 * x1.x + w1 * x1.y + w2 * x1.z + w3 * x1.w;
            }
        }
        if (row0 < N_NODESC) {
            #pragma unroll
            for (int j = 0; j < 5; j++) out[(size_t)row0 * NCLASS + c0 + j] = a0[j] + b2f[c0 + j];
        }
        if (row1 < N_NODESC) {
            #pragma unroll
            for (int j = 0; j < 5; j++) out[(size_t)row1 * NCLASS + c0 + j] = a1[j] + b2f[c0 + j];
        }
    }
}

extern "C" void kernel_launch(void* const* d_in, const int* in_sizes, int n_in,
                              void* d_out, int out_size, void* d_ws, size_t ws_size,
                              hipStream_t stream) {
    const float* h    = (const float*)d_in[0];
    const int*   src  = (const int*)d_in[1];
    const int*   dst  = (const int*)d_in[2];
    const float* bn_g = (const float*)d_in[3];
    const float* bn_b = (const float*)d_in[4];
    const float* W1   = (const float*)d_in[5];
    const float* b1   = (const float*)d_in[6];
    const float* g2   = (const float*)d_in[7];
    const float* be2  = (const float*)d_in[8];
    const float* W2   = (const float*)d_in[9];
    const float* b2   = (const float*)d_in[10];
    float* out = (float*)d_out;

    // workspace layout (floats; ~55 MB total)
    float* ws      = (float*)d_ws;
    float* nrm     = ws;                                   // 50000
    int*   deg     = (int*)(ws + N_NODESC);                // 50000
    int*   cursor  = deg + N_NODESC;                       // 50000
    int*   rowptr  = cursor + N_NODESC;                    // pad 50016
    int*   bsums   = rowptr + 50016;                       // 256
    int*   boff    = bsums + 256;                          // 256
    int*   csr     = boff + 256;                           // 600000
    float* partials = (float*)(csr + N_EDGESC);            // 196*256 = 50176
    float* mu      = partials + STAT_BLOCKS * 256;         // 128
    float* rstd    = mu + DDIM;                            // 128
    float* W2f     = rstd + DDIM;                          // 5120
    float* b2f     = W2f + DDIM * NCLASS;                  // pad 64
    unsigned short* W1T = (unsigned short*)(b2f + 64);     // 16384 ushort (8192 f)
    unsigned short* Hb  = (unsigned short*)((float*)W1T + 8192);   // 6.4M ushort (3.2M f)
    unsigned short* Pb  = (unsigned short*)((float*)Hb + 3200000); // 6.4M ushort
    float* X       = (float*)((float*)Pb + 3200000);       // 6.4M floats

    (void)in_sizes; (void)n_in; (void)out_size; (void)ws_size;

    hipMemsetAsync(deg, 0, N_NODESC * sizeof(int), stream);
    deg_kernel<<<(N_EDGESC + 255) / 256, 256, 0, stream>>>(dst, deg);
    scan1_kernel<<<STAT_BLOCKS, 256, 0, stream>>>(deg, rowptr, bsums);
    scan2_kernel<<<1, 256, 0, stream>>>(bsums, boff);
    scan3_kernel<<<STAT_BLOCKS, 256, 0, stream>>>(rowptr, boff, deg, cursor, nrm);
    fill_kernel<<<(N_EDGESC + 255) / 256, 256, 0, stream>>>(src, dst, cursor, csr);
    sortrows_kernel<<<SORT_BLOCKS, 128, 0, stream>>>(rowptr, csr);
    hconv_kernel<<<(N_NODESC * DDIM / 8 + 255) / 256, 256, 0, stream>>>(h, Hb);
    w1prep_kernel<<<(DDIM * DDIM + 255) / 256, 256, 0, stream>>>(W1, W1T);

    // layer 0: Pb = nrm * S(nrm * Hb)
    gather_kernel<false><<<GATHER_BLOCKS, 256, 0, stream>>>(Hb, nrm, rowptr, csr,
                                                            nullptr, nullptr, nullptr, nullptr, Pb);
    stats_bf16_kernel<<<STAT_BLOCKS, 256, 0, stream>>>(Pb, partials);
    finalize_kernel<<<1, 1024, 0, stream>>>(partials, mu, rstd);
    // layer 1: Hb = nrm * S(nrm * relu(BN(Pb)))
    gather_kernel<true><<<GATHER_BLOCKS, 256, 0, stream>>>(Pb, nrm, rowptr, csr,
                                                           mu, rstd, bn_g, bn_b, Hb);
    stats_bf16_kernel<<<STAT_BLOCKS, 256, 0, stream>>>(Hb, partials);
    finalize_kernel<<<1, 1024, 0, stream>>>(partials, mu, rstd);
    // layer 2
    gather_kernel<true><<<GATHER_BLOCKS, 256, 0, stream>>>(Hb, nrm, rowptr, csr,
                                                           mu, rstd, bn_g, bn_b, Pb);
    stats_bf16_kernel<<<STAT_BLOCKS, 256, 0, stream>>>(Pb, partials);
    finalize_kernel<<<1, 1024, 0, stream>>>(partials, mu, rstd);
    // layer 3
    gather_kernel<true><<<GATHER_BLOCKS, 256, 0, stream>>>(Pb, nrm, rowptr, csr,
                                                           mu, rstd, bn_g, bn_b, Hb);
    stats_bf16_kernel<<<STAT_BLOCKS, 256, 0, stream>>>(Hb, partials);
    finalize_kernel<<<1, 1024, 0, stream>>>(partials, mu, rstd);

    // epilogue: X = relu(BN(Hb)) @ W1 + b1 (MFMA); BN2 folded into W2; out = X @ W2f + b2f
    linear1_mfma<<<782, 256, 0, stream>>>(Hb, W1T, b1, mu, rstd, bn_g, bn_b, X);
    stats_f32_kernel<<<STAT_BLOCKS, 256, 0, stream>>>(X, partials);
    finalize_kernel<<<1, 1024, 0, stream>>>(partials, mu, rstd);
    fold_kernel<<<1, 256, 0, stream>>>(W2, b2, g2, be2, mu, rstd, W2f, b2f);
    linear2_kernel<<<512, 256, 0, stream>>>(X, W2f, b2f, out);
}